// Round 8
// baseline (256.083 us; speedup 1.0000x reference)
//
#include <hip/hip_runtime.h>
#include <math.h>

typedef __bf16 bf16;
typedef __bf16 bf16x8 __attribute__((ext_vector_type(8)));
typedef __bf16 bf16x4 __attribute__((ext_vector_type(4)));
typedef float f32x4 __attribute__((ext_vector_type(4)));

// B=2, C=512, L=4096, NH=4, HD=128, GROUPS=32. K of every GEMM = 512.
#define QSCALE (0.08838834764831845f * 1.4426950408889634f)  // 1/sqrt(128) * log2(e)

__device__ __forceinline__ void gll16(const bf16* g, bf16* l) {
    __builtin_amdgcn_global_load_lds((const __attribute__((address_space(1))) void*)g,
                                     (__attribute__((address_space(3))) void*)l, 16, 0, 0);
}

// ---------------- fused: weight fp32->bf16 convert (blocks 0..1023) + GN partial stats (1024..1279) ----
__global__ void k_pre(const float* __restrict__ wqkv, const float* __restrict__ wproj,
                      const float* __restrict__ x,
                      bf16* __restrict__ wqkv_b, bf16* __restrict__ wproj_b,
                      float* __restrict__ part) {
    int blk = blockIdx.x;
    if (blk < 1024) {
        int i = blk * 256 + threadIdx.x;   // float4 index
        const int n1 = (1536 * 512) / 4;
        float4 v;
        bf16* dst;
        if (i < n1) { v = ((const float4*)wqkv)[i];      dst = wqkv_b + (size_t)i * 4; }
        else        { v = ((const float4*)wproj)[i - n1]; dst = wproj_b + (size_t)(i - n1) * 4; }
        bf16x4 o;
        o[0] = (bf16)v.x; o[1] = (bf16)v.y; o[2] = (bf16)v.z; o[3] = (bf16)v.w;
        *(bf16x4*)dst = o;
        return;
    }
    int b2 = blk - 1024;
    int grp = b2 >> 2, p = b2 & 3;
    const float4* src = (const float4*)(x + (size_t)grp * 65536 + (size_t)p * 16384);
    float s = 0.f, ss = 0.f;
    for (int it = 0; it < 16; ++it) {
        float4 v = src[threadIdx.x + it * 256];
        s  += v.x + v.y + v.z + v.w;
        ss += v.x * v.x + v.y * v.y + v.z * v.z + v.w * v.w;
    }
    for (int off = 32; off; off >>= 1) { s += __shfl_down(s, off); ss += __shfl_down(ss, off); }
    __shared__ float rs[4], rss[4];
    int wave = threadIdx.x >> 6;
    if ((threadIdx.x & 63) == 0) { rs[wave] = s; rss[wave] = ss; }
    __syncthreads();
    if (threadIdx.x == 0) {
        part[(grp * 4 + p) * 2]     = rs[0] + rs[1] + rs[2] + rs[3];
        part[(grp * 4 + p) * 2 + 1] = rss[0] + rss[1] + rss[2] + rss[3];
    }
}

// ---------------- GN normalize + transpose (stats finalized in-block): x[b][c][l] -> xn_t[b][l][c] ----
__global__ __launch_bounds__(256) void k_gn_norm_t(const float* __restrict__ x, const float* __restrict__ gw,
                                                   const float* __restrict__ gb, const float* __restrict__ part,
                                                   bf16* __restrict__ xn_t) {
    __shared__ float sX[64 * 69];
    __shared__ float sMean[4], sRstd[4];
    int b = blockIdx.z, c0 = blockIdx.y * 64, l0 = blockIdx.x * 64;
    int t = threadIdx.x;
    if (t < 4) {
        int g = b * 32 + (c0 >> 4) + t;
        float S = 0.f, SS = 0.f;
        for (int p = 0; p < 4; ++p) { S += part[(g * 4 + p) * 2]; SS += part[(g * 4 + p) * 2 + 1]; }
        float mean = S * (1.f / 65536.f);
        float var  = SS * (1.f / 65536.f) - mean * mean;
        sMean[t] = mean;
        sRstd[t] = rsqrtf(var + 1e-5f);
    }
    __syncthreads();
    int cr = t >> 4, lq = t & 15;
    const float* xp = x + ((size_t)(b * 512 + c0)) * 4096 + l0;
    for (int i = 0; i < 4; ++i) {
        int c = cr + i * 16;
        int cg = c0 + c;
        float mean = sMean[c >> 4], rstd = sRstd[c >> 4];
        float ga = gw[cg] * rstd;
        float be = gb[cg] - mean * ga;
        float4 v = *(const float4*)(xp + (size_t)c * 4096 + lq * 4);
        float* d = &sX[c * 69 + lq * 4];
        d[0] = v.x * ga + be; d[1] = v.y * ga + be; d[2] = v.z * ga + be; d[3] = v.w * ga + be;
    }
    __syncthreads();
    int lr = t >> 3, cp = t & 7;
    bf16* dst = xn_t + ((size_t)b * 4096 + l0) * 512 + c0;
    for (int i = 0; i < 2; ++i) {
        int l = lr + i * 32;
        bf16x8 o;
        for (int j = 0; j < 8; ++j) o[j] = (bf16)sX[(cp * 8 + j) * 69 + l];
        *(bf16x8*)(dst + (size_t)l * 512 + cp * 8) = o;
    }
}

// ---------------- fused qkv+v GEMM (m97 structure): out[o][l] for o<1024 -> qkT[l][o]; o>=1024 -> v ----
// BM=BN=128, BK=64, 8 k-steps, single-buffer LDS + 2 barriers/step. T1 XCD-chunked swizzle.
// 768 blocks = 3/CU co-resident (the prerequisite that hides the post-stage vmcnt drain).
__global__ __launch_bounds__(256, 3) void k_gemm_qkv(
    const bf16* __restrict__ A, const bf16* __restrict__ W, const float* __restrict__ bias,
    bf16* __restrict__ qkT, bf16* __restrict__ vb) {
    __shared__ bf16 smem[17408];   // stage: A 128x64 @0, B 128x64 @8192 (32KB); epilogue [128][136] 34816B
    int linear = blockIdx.x + 12 * blockIdx.y + 384 * blockIdx.z;
    int swz = (linear & 7) * 96 + (linear >> 3);   // bijective: 768 = 8 * 96
    int n0 = (swz % 12) * 128;
    int m0 = ((swz / 12) % 32) * 128;
    int bz = swz / 384;
    int tid = threadIdx.x, lane = tid & 63, wave = tid >> 6;
    int lo = lane & 15, quad = lane >> 4;
    int lr = lane >> 3, ls = lane & 7;
    int mw = (wave >> 1) * 64, nw = (wave & 1) * 64;
    const bf16* aptr[4]; int adst[4];
    const bf16* bptr[4]; int bdst[4];
    for (int i = 0; i < 4; ++i) {
        int r0 = wave * 32 + i * 8;
        int row = r0 + lr;
        aptr[i] = A + (size_t)bz * (4096 * 512) + (size_t)(m0 + row) * 512 + ((ls ^ (row & 7)) * 8);
        adst[i] = r0 * 64;
        bptr[i] = W + (size_t)(n0 + row) * 512 + ((ls ^ (row & 7)) * 8);
        bdst[i] = 8192 + r0 * 64;
    }
    f32x4 acc[4][4] = {};
    for (int step = 0; step < 8; ++step) {
        __syncthreads();   // frag reads of previous step done
        for (int i = 0; i < 4; ++i) {
            gll16(aptr[i], &smem[adst[i]]); aptr[i] += 64;
            gll16(bptr[i], &smem[bdst[i]]); bptr[i] += 64;
        }
        __syncthreads();   // staging complete (vmcnt drain)
        const bf16* sA = smem;
        const bf16* sB = smem + 8192;
        for (int kk = 0; kk < 2; ++kk) {
            bf16x8 af[4], bfr[4];
            int sw = ((kk * 4 + quad) ^ (lo & 7)) * 8;
            for (int t = 0; t < 4; ++t) af[t]  = *(const bf16x8*)&sA[(mw + t * 16 + lo) * 64 + sw];
            for (int t = 0; t < 4; ++t) bfr[t] = *(const bf16x8*)&sB[(nw + t * 16 + lo) * 64 + sw];
            for (int mt = 0; mt < 4; ++mt)
                for (int nt = 0; nt < 4; ++nt)
                    acc[mt][nt] = __builtin_amdgcn_mfma_f32_16x16x32_bf16(af[mt], bfr[nt], acc[mt][nt], 0, 0, 0);
        }
    }
    __syncthreads();
    bf16* sT = smem;
    bool isv = (n0 >= 1024);
    float sc = (n0 < 512) ? QSCALE : 1.f;
    for (int mt = 0; mt < 4; ++mt)
        for (int nt = 0; nt < 4; ++nt) {
            int c = nw + nt * 16 + lo;
            float bv = bias[n0 + c];
            for (int r = 0; r < 4; ++r) {
                int l = mw + mt * 16 + quad * 4 + r;
                float v = (acc[mt][nt][r] + bv) * sc;
                if (isv) sT[c * 136 + l] = (bf16)v;   // [128 c][128 l]
                else     sT[l * 136 + c] = (bf16)v;   // [128 l][128 o]
            }
        }
    __syncthreads();
    int row = tid >> 1, hh = tid & 1;
    if (isv) {
        bf16* dst = vb + (size_t)bz * (512 * 4096) + (size_t)(n0 - 1024 + row) * 4096 + m0;
        for (int j = 0; j < 8; ++j) {
            int ch = hh + j * 2;
            *(bf16x8*)(dst + ch * 8) = *(const bf16x8*)&sT[row * 136 + ch * 8];
        }
    } else {
        bf16* dst = qkT + (size_t)bz * (4096 * 1024) + (size_t)(m0 + row) * 1024 + n0;
        for (int j = 0; j < 8; ++j) {
            int ch = hh + j * 2;
            *(bf16x8*)(dst + ch * 8) = *(const bf16x8*)&sT[row * 136 + ch * 8];
        }
    }
}

// ---------------- proj GEMM (R0/R5-verified dbuf structure): D[m=co][n=l] + bias + resid -> fp32 ----
// BM=64, BN=128, BK=64, double-buffered, 1 barrier/step: prefetch issued AFTER the barrier, so the
// next barrier's vmcnt drain waits on loads issued a full compute-phase earlier. Works at 512 blocks
// (2/CU). (m97 2-barrier variant regressed here: 256 tiles = 1 block/CU exposes the drain — R7.)
__global__ __launch_bounds__(256, 3) void k_gemm_proj(
    const bf16* __restrict__ W, const bf16* __restrict__ Bm,
    const float* __restrict__ bias_m,
    float* __restrict__ outf, const float* __restrict__ resid) {
    constexpr int BUF = (64 + 128) * 64;
    __shared__ bf16 smem[2 * BUF];
    int bz = blockIdx.z;
    int m0 = blockIdx.y * 64, n0 = blockIdx.x * 128;
    int tid = threadIdx.x, lane = tid & 63, wave = tid >> 6;
    int lo = lane & 15, quad = lane >> 4;
    int lr = lane >> 3, ls = lane & 7;
    int mw = (wave >> 1) * 32, nw = (wave & 1) * 64;
    const bf16* aptr[2]; int adst[2];
    for (int i = 0; i < 2; ++i) {
        int r0 = wave * 16 + i * 8;
        int row = r0 + lr;
        aptr[i] = W + (size_t)(m0 + row) * 512 + ((ls ^ (row & 7)) * 8);
        adst[i] = r0 * 64;
    }
    const bf16* bptr[4]; int bdst[4];
    for (int i = 0; i < 4; ++i) {
        int r0 = wave * 32 + i * 8;
        int row = r0 + lr;
        bptr[i] = Bm + (size_t)bz * (4096 * 512) + (size_t)(n0 + row) * 512 + ((ls ^ (row & 7)) * 8);
        bdst[i] = 64 * 64 + r0 * 64;
    }
    f32x4 acc[2][4] = {};
    for (int i = 0; i < 2; ++i) { gll16(aptr[i], &smem[adst[i]]); aptr[i] += 64; }
    for (int i = 0; i < 4; ++i) { gll16(bptr[i], &smem[bdst[i]]); bptr[i] += 64; }
    for (int step = 0; step < 8; ++step) {
        int cur = step & 1;
        __syncthreads();
        if (step < 7) {
            bf16* nb = &smem[(cur ^ 1) * BUF];
            for (int i = 0; i < 2; ++i) { gll16(aptr[i], nb + adst[i]); aptr[i] += 64; }
            for (int i = 0; i < 4; ++i) { gll16(bptr[i], nb + bdst[i]); bptr[i] += 64; }
        }
        const bf16* sA = &smem[cur * BUF];
        const bf16* sB = sA + 64 * 64;
        for (int kk = 0; kk < 2; ++kk) {
            bf16x8 af[2], bfr[4];
            int sw = ((kk * 4 + quad) ^ (lo & 7)) * 8;
            for (int t = 0; t < 2; ++t) af[t]  = *(const bf16x8*)&sA[(mw + t * 16 + lo) * 64 + sw];
            for (int t = 0; t < 4; ++t) bfr[t] = *(const bf16x8*)&sB[(nw + t * 16 + lo) * 64 + sw];
            for (int mt = 0; mt < 2; ++mt)
                for (int nt = 0; nt < 4; ++nt)
                    acc[mt][nt] = __builtin_amdgcn_mfma_f32_16x16x32_bf16(af[mt], bfr[nt], acc[mt][nt], 0, 0, 0);
        }
    }
    for (int mt = 0; mt < 2; ++mt) {
        int rowb = m0 + mw + mt * 16 + quad * 4;
        for (int nt = 0; nt < 4; ++nt) {
            int col = n0 + nw + nt * 16 + lo;
            for (int r = 0; r < 4; ++r) {
                int row = rowb + r;
                size_t idx = (size_t)bz * (512 * 4096) + (size_t)row * 4096 + col;
                outf[idx] = acc[mt][nt][r] + bias_m[row] + resid[idx];
            }
        }
    }
}

// ---------------- flash attention: 128q block, KVBLK=128, 8 waves = 2 q-halves x 4 key-quarters ----
// DS-redundancy cut: K/V frags read 2x (was 4x). Wave w: a=w&1 (64 q), b2=w>>1 (32 keys of 128).
// LDS (exactly 160 KiB): K dbuf @0 (2x32KB) | V dbuf @65536 (2x32KB) | sPe @131072 ([2 a][64 q][128 k]
// bf16, XOR-chunk swizzled, 32KB). P is a same-wave LDS round trip. One barrier/iter.
// R6 retry: kernel was correctness-verified; failure was __launch_bounds__(512,2) capping VGPR at 128
// (measured) -> spills. A 512-thread block mandates 2 waves/SIMD = 256 VGPR budget; (512,1) opens it.
__global__ __launch_bounds__(512, 1) void k_attn(const bf16* __restrict__ qkT, const bf16* __restrict__ vmat,
                                                 bf16* __restrict__ attnT) {
    __shared__ __align__(16) char smem[163840];
    bf16* sE = (bf16*)smem;
    int bidx = blockIdx.x;
    int bh = bidx & 7;
    int bb = bh >> 2, h = bh & 3;
    int l0 = (bidx >> 3) * 128;
    int tid = threadIdx.x, lane = tid & 63, wave = tid >> 6;
    int lo = lane & 15, quad = lane >> 4;
    int a = wave & 1, b2 = wave >> 1;
    const bf16* qbase = qkT + ((size_t)bb * 4096 + l0) * 1024 + h * 128;
    const bf16* kbase = qkT + (size_t)bb * 4096 * 1024 + 512 + h * 128;
    const bf16* vbase = vmat + (size_t)(bb * 512 + h * 128) * 4096;
    // ---- stage Q (128x128) into kbuf0, pull frags to regs ----
    for (int i = 0; i < 4; ++i) {
        int r0 = wave * 16 + i * 4;
        int row = r0 + quad;
        gll16(qbase + (size_t)row * 1024 + ((lo ^ (row & 15)) * 8), sE + r0 * 128);
    }
    __syncthreads();
    bf16x8 qf[4][4];
    for (int nt = 0; nt < 4; ++nt) {
        int row = a * 64 + nt * 16 + lo;
        for (int kk = 0; kk < 4; ++kk)
            qf[nt][kk] = *(const bf16x8*)&sE[row * 128 + (((kk * 4 + quad) ^ lo) * 8)];
    }
    __syncthreads();   // all q-frag reads done before K(0) staging overwrites
    // ---- staging descriptors: 4 K + 4 V chunks per wave (16 rows each of 128x256B tiles) ----
    const bf16* kp[4]; int kdst[4];
    const bf16* vp[4]; int vdst[4];
    for (int i = 0; i < 4; ++i) {
        int r0 = wave * 16 + i * 4;
        int row = r0 + quad;
        kp[i] = kbase + (size_t)row * 1024 + ((lo ^ (row & 15)) * 8);
        kdst[i] = r0 * 128;
        vp[i] = vbase + (size_t)row * 4096 + ((lo ^ (row & 15)) * 8);
        vdst[i] = 32768 + r0 * 128;
    }
    char* sPb = smem + 131072 + a * 16384;   // [64 q][256 B], XOR-chunk swizzled
    float l_r[4] = {};
    f32x4 oacc[8][4] = {};
    // prologue: stage K(0), V(0) into buf 0
    for (int i = 0; i < 4; ++i) { gll16(kp[i], sE + kdst[i]); kp[i] += 131072; }
    for (int i = 0; i < 4; ++i) { gll16(vp[i], sE + vdst[i]); vp[i] += 128; }
    for (int it = 0; it < 32; ++it) {
        int cur = it & 1;
        __syncthreads();   // buf[cur] staged; readers of buf[cur^1] done
        if (it < 31) {
            int nb = (cur ^ 1) * 16384;
            for (int i = 0; i < 4; ++i) { gll16(kp[i], sE + nb + kdst[i]); kp[i] += 131072; }
            for (int i = 0; i < 4; ++i) { gll16(vp[i], sE + nb + vdst[i]); vp[i] += 128; }
        }
        const bf16* sK = sE + cur * 16384;
        const bf16* sV = sE + 32768 + cur * 16384;
        // K frags for the wave's 32-key quarter
        bf16x8 kf[2][4];
        for (int mt = 0; mt < 2; ++mt) {
            int krow = b2 * 32 + mt * 16 + lo;
            for (int kk = 0; kk < 4; ++kk)
                kf[mt][kk] = *(const bf16x8*)&sK[krow * 128 + (((kk * 4 + quad) ^ lo) * 8)];
        }
        // QK^T + softmax per nt: S^T[32 keys][16 q], P = exp2(s), write to sPe (own slice)
        for (int nt = 0; nt < 4; ++nt) {
            f32x4 s0 = {}, s1 = {};
            __builtin_amdgcn_s_setprio(1);
            for (int kk = 0; kk < 4; ++kk)
                s0 = __builtin_amdgcn_mfma_f32_16x16x32_bf16(kf[0][kk], qf[nt][kk], s0, 0, 0, 0);
            for (int kk = 0; kk < 4; ++kk)
                s1 = __builtin_amdgcn_mfma_f32_16x16x32_bf16(kf[1][kk], qf[nt][kk], s1, 0, 0, 0);
            __builtin_amdgcn_s_setprio(0);
            float sm = 0.f;
            int qrow = (nt * 16 + lo) * 256;
            {
                bf16x4 pk;
                for (int r = 0; r < 4; ++r) {
                    float pv = __builtin_amdgcn_exp2f(s0[r]);
                    sm += pv; pk[r] = (bf16)pv;
                }
                *(bf16x4*)&sPb[qrow + ((((b2 << 2) + (quad >> 1)) ^ lo) << 4) + ((quad & 1) << 3)] = pk;
            }
            {
                bf16x4 pk;
                for (int r = 0; r < 4; ++r) {
                    float pv = __builtin_amdgcn_exp2f(s1[r]);
                    sm += pv; pk[r] = (bf16)pv;
                }
                *(bf16x4*)&sPb[qrow + ((((b2 << 2) + 2 + (quad >> 1)) ^ lo) << 4) + ((quad & 1) << 3)] = pk;
            }
            l_r[nt] += sm;
        }
        // P frags (B-operand): same-wave round trip, own 32-k slice
        bf16x8 pf[4];
        for (int nt = 0; nt < 4; ++nt)
            pf[nt] = *(const bf16x8*)&sPb[(nt * 16 + lo) * 256 + ((((b2 << 2) + quad) ^ lo) << 4)];
        // PV: O^T[128 vc][64 q] += V . P over the wave's 32 keys
        __builtin_amdgcn_s_setprio(1);
        for (int mt2 = 0; mt2 < 8; ++mt2) {
            bf16x8 vf = *(const bf16x8*)&sV[(mt2 * 16 + lo) * 128 + ((((b2 << 2) + quad) ^ lo) * 8)];
            for (int nt = 0; nt < 4; ++nt)
                oacc[mt2][nt] = __builtin_amdgcn_mfma_f32_16x16x32_bf16(vf, pf[nt], oacc[mt2][nt], 0, 0, 0);
        }
        __builtin_amdgcn_s_setprio(0);
    }
    // ---- merge: l reduction, then 4-way pairwise O tree ----
    for (int nt = 0; nt < 4; ++nt) {
        l_r[nt] += __shfl_xor(l_r[nt], 16);
        l_r[nt] += __shfl_xor(l_r[nt], 32);
    }
    __syncthreads();   // all loop LDS reads done
    float* sStat = (float*)(smem + 139264);   // [128 q][4 b2] f32 (in dead sPe region, disjoint from sOm)
    if (quad == 0)
        for (int nt = 0; nt < 4; ++nt)
            sStat[(a * 64 + nt * 16 + lo) * 4 + b2] = l_r[nt];
    __syncthreads();
    float* sOmA = (float*)smem;               // [2 a][128 vc][68 q] f32 = 69632 B
    float* sOmB = (float*)(smem + 69632);     // same, ends 139264
    float inv[4];
    if (b2 == 0)
        for (int nt = 0; nt < 4; ++nt) {
            const float* st = &sStat[(a * 64 + nt * 16 + lo) * 4];
            inv[nt] = 1.f / (st[0] + st[1] + st[2] + st[3]);
        }
    // t1: b2=1 -> sOmA, b2=3 -> sOmB
    if (b2 == 1 || b2 == 3) {
        float* dm = (b2 == 1 ? sOmA : sOmB) + a * 8704;
        for (int mt2 = 0; mt2 < 8; ++mt2)
            for (int nt = 0; nt < 4; ++nt)
                for (int r = 0; r < 4; ++r)
                    dm[(mt2 * 16 + quad * 4 + r) * 68 + nt * 16 + lo] = oacc[mt2][nt][r];
    }
    __syncthreads();
    // t2: b2=0 += sOmA (0+1), b2=2 += sOmB (2+3)
    if (b2 == 0 || b2 == 2) {
        const float* sm2 = (b2 == 0 ? sOmA : sOmB) + a * 8704;
        for (int mt2 = 0; mt2 < 8; ++mt2)
            for (int nt = 0; nt < 4; ++nt)
                for (int r = 0; r < 4; ++r)
                    oacc[mt2][nt][r] += sm2[(mt2 * 16 + quad * 4 + r) * 68 + nt * 16 + lo];
    }
    __syncthreads();
    // t3: b2=2 writes (2+3) -> sOmA
    if (b2 == 2) {
        float* dm = sOmA + a * 8704;
        for (int mt2 = 0; mt2 < 8; ++mt2)
            for (int nt = 0; nt < 4; ++nt)
                for (int r = 0; r < 4; ++r)
                    dm[(mt2 * 16 + quad * 4 + r) * 68 + nt * 16 + lo] = oacc[mt2][nt][r];
    }
    __syncthreads();
    // t4: b2=0 finalizes: (0+1)+(2+3), *inv, write sOut [128 q][136] bf16 @69632 (over dead sOmB)
    bf16* sOut = (bf16*)(smem + 69632);
    if (b2 == 0) {
        const float* sm2 = sOmA + a * 8704;
        for (int mt2 = 0; mt2 < 8; ++mt2)
            for (int nt = 0; nt < 4; ++nt)
                for (int r = 0; r < 4; ++r) {
                    int vc = mt2 * 16 + quad * 4 + r;
                    float v = (oacc[mt2][nt][r] + sm2[vc * 68 + nt * 16 + lo]) * inv[nt];
                    sOut[(a * 64 + nt * 16 + lo) * 136 + vc] = (bf16)v;
                }
    }
    __syncthreads();
    // t5: vectorized store
    bf16* dst = attnT + ((size_t)bb * 4096 + l0) * 512 + h * 128;
    for (int i = 0; i < 4; ++i) {
        int row = (tid >> 4) + i * 32;
        int chunk = tid & 15;
        bf16x8 v = *(const bf16x8*)&sOut[row * 136 + chunk * 8];
        *(bf16x8*)(dst + (size_t)row * 512 + chunk * 8) = v;
    }
}

// ---------------- launcher ----------------
extern "C" void kernel_launch(void* const* d_in, const int* in_sizes, int n_in,
                              void* d_out, int out_size, void* d_ws, size_t ws_size,
                              hipStream_t stream) {
    const float* x      = (const float*)d_in[0];
    const float* gn_w   = (const float*)d_in[1];
    const float* gn_b   = (const float*)d_in[2];
    const float* w_qkv  = (const float*)d_in[3];
    const float* b_qkv  = (const float*)d_in[4];
    const float* w_proj = (const float*)d_in[5];
    const float* b_proj = (const float*)d_in[6];
    float* out = (float*)d_out;
    char* ws = (char*)d_ws;
    bf16* wqkv_b  = (bf16*)(ws + 0);
    bf16* wproj_b = (bf16*)(ws + 1572864);
    bf16* xn_t    = (bf16*)(ws + 2097152);
    bf16* qkT     = (bf16*)(ws + 10485760);
    bf16* vb      = (bf16*)(ws + 27262976);
    bf16* attnT   = (bf16*)(ws + 35651584);
    float* part   = (float*)(ws + 44040192);

    k_pre<<<1280, 256, 0, stream>>>(w_qkv, w_proj, x, wqkv_b, wproj_b, part);
    k_gn_norm_t<<<dim3(64, 8, 2), 256, 0, stream>>>(x, gn_w, gn_b, part, xn_t);
    // fused qkv+v: o<1024 -> qkT[l][o] (q scaled), o>=1024 -> vb[c][l]
    k_gemm_qkv<<<dim3(12, 32, 2), 256, 0, stream>>>(xn_t, wqkv_b, b_qkv, qkT, vb);
    k_attn<<<256, 512, 0, stream>>>(qkT, vb, attnT);
    k_gemm_proj<<<dim3(32, 8, 2), 256, 0, stream>>>(wproj_b, attnT, b_proj, out, x);
}

// Round 9
// 188.878 us; speedup vs baseline: 1.3558x; 1.3558x over previous
//
#include <hip/hip_runtime.h>
#include <math.h>

typedef __bf16 bf16;
typedef __bf16 bf16x8 __attribute__((ext_vector_type(8)));
typedef __bf16 bf16x4 __attribute__((ext_vector_type(4)));
typedef float f32x4 __attribute__((ext_vector_type(4)));

// B=2, C=512, L=4096, NH=4, HD=128, GROUPS=32. K of every GEMM = 512.
#define QSCALE (0.08838834764831845f * 1.4426950408889634f)  // 1/sqrt(128) * log2(e)

__device__ __forceinline__ void gll16(const bf16* g, bf16* l) {
    __builtin_amdgcn_global_load_lds((const __attribute__((address_space(1))) void*)g,
                                     (__attribute__((address_space(3))) void*)l, 16, 0, 0);
}

// ---------------- fused: weight fp32->bf16 convert (blocks 0..1023) + GN partial stats (1024..1279) ----
__global__ void k_pre(const float* __restrict__ wqkv, const float* __restrict__ wproj,
                      const float* __restrict__ x,
                      bf16* __restrict__ wqkv_b, bf16* __restrict__ wproj_b,
                      float* __restrict__ part) {
    int blk = blockIdx.x;
    if (blk < 1024) {
        int i = blk * 256 + threadIdx.x;   // float4 index
        const int n1 = (1536 * 512) / 4;
        float4 v;
        bf16* dst;
        if (i < n1) { v = ((const float4*)wqkv)[i];      dst = wqkv_b + (size_t)i * 4; }
        else        { v = ((const float4*)wproj)[i - n1]; dst = wproj_b + (size_t)(i - n1) * 4; }
        bf16x4 o;
        o[0] = (bf16)v.x; o[1] = (bf16)v.y; o[2] = (bf16)v.z; o[3] = (bf16)v.w;
        *(bf16x4*)dst = o;
        return;
    }
    int b2 = blk - 1024;
    int grp = b2 >> 2, p = b2 & 3;
    const float4* src = (const float4*)(x + (size_t)grp * 65536 + (size_t)p * 16384);
    float s = 0.f, ss = 0.f;
    for (int it = 0; it < 16; ++it) {
        float4 v = src[threadIdx.x + it * 256];
        s  += v.x + v.y + v.z + v.w;
        ss += v.x * v.x + v.y * v.y + v.z * v.z + v.w * v.w;
    }
    for (int off = 32; off; off >>= 1) { s += __shfl_down(s, off); ss += __shfl_down(ss, off); }
    __shared__ float rs[4], rss[4];
    int wave = threadIdx.x >> 6;
    if ((threadIdx.x & 63) == 0) { rs[wave] = s; rss[wave] = ss; }
    __syncthreads();
    if (threadIdx.x == 0) {
        part[(grp * 4 + p) * 2]     = rs[0] + rs[1] + rs[2] + rs[3];
        part[(grp * 4 + p) * 2 + 1] = rss[0] + rss[1] + rss[2] + rss[3];
    }
}

// ---------------- GN normalize + transpose (stats finalized in-block): x[b][c][l] -> xn_t[b][l][c] ----
__global__ __launch_bounds__(256) void k_gn_norm_t(const float* __restrict__ x, const float* __restrict__ gw,
                                                   const float* __restrict__ gb, const float* __restrict__ part,
                                                   bf16* __restrict__ xn_t) {
    __shared__ float sX[64 * 69];
    __shared__ float sMean[4], sRstd[4];
    int b = blockIdx.z, c0 = blockIdx.y * 64, l0 = blockIdx.x * 64;
    int t = threadIdx.x;
    if (t < 4) {
        int g = b * 32 + (c0 >> 4) + t;
        float S = 0.f, SS = 0.f;
        for (int p = 0; p < 4; ++p) { S += part[(g * 4 + p) * 2]; SS += part[(g * 4 + p) * 2 + 1]; }
        float mean = S * (1.f / 65536.f);
        float var  = SS * (1.f / 65536.f) - mean * mean;
        sMean[t] = mean;
        sRstd[t] = rsqrtf(var + 1e-5f);
    }
    __syncthreads();
    int cr = t >> 4, lq = t & 15;
    const float* xp = x + ((size_t)(b * 512 + c0)) * 4096 + l0;
    for (int i = 0; i < 4; ++i) {
        int c = cr + i * 16;
        int cg = c0 + c;
        float mean = sMean[c >> 4], rstd = sRstd[c >> 4];
        float ga = gw[cg] * rstd;
        float be = gb[cg] - mean * ga;
        float4 v = *(const float4*)(xp + (size_t)c * 4096 + lq * 4);
        float* d = &sX[c * 69 + lq * 4];
        d[0] = v.x * ga + be; d[1] = v.y * ga + be; d[2] = v.z * ga + be; d[3] = v.w * ga + be;
    }
    __syncthreads();
    int lr = t >> 3, cp = t & 7;
    bf16* dst = xn_t + ((size_t)b * 4096 + l0) * 512 + c0;
    for (int i = 0; i < 2; ++i) {
        int l = lr + i * 32;
        bf16x8 o;
        for (int j = 0; j < 8; ++j) o[j] = (bf16)sX[(cp * 8 + j) * 69 + l];
        *(bf16x8*)(dst + (size_t)l * 512 + cp * 8) = o;
    }
}

// ---------------- fused qkv+v GEMM (m97 structure): out[o][l] for o<1024 -> qkT[l][o]; o>=1024 -> v ----
// BM=BN=128, BK=64, 8 k-steps, single-buffer LDS + 2 barriers/step. T1 XCD-chunked swizzle.
// 768 blocks = 3/CU co-resident (prerequisite that hides the post-stage vmcnt drain).
__global__ __launch_bounds__(256, 3) void k_gemm_qkv(
    const bf16* __restrict__ A, const bf16* __restrict__ W, const float* __restrict__ bias,
    bf16* __restrict__ qkT, bf16* __restrict__ vb) {
    __shared__ bf16 smem[17408];   // stage: A 128x64 @0, B 128x64 @8192 (32KB); epilogue [128][136] 34816B
    int linear = blockIdx.x + 12 * blockIdx.y + 384 * blockIdx.z;
    int swz = (linear & 7) * 96 + (linear >> 3);   // bijective: 768 = 8 * 96
    int n0 = (swz % 12) * 128;
    int m0 = ((swz / 12) % 32) * 128;
    int bz = swz / 384;
    int tid = threadIdx.x, lane = tid & 63, wave = tid >> 6;
    int lo = lane & 15, quad = lane >> 4;
    int lr = lane >> 3, ls = lane & 7;
    int mw = (wave >> 1) * 64, nw = (wave & 1) * 64;
    const bf16* aptr[4]; int adst[4];
    const bf16* bptr[4]; int bdst[4];
    for (int i = 0; i < 4; ++i) {
        int r0 = wave * 32 + i * 8;
        int row = r0 + lr;
        aptr[i] = A + (size_t)bz * (4096 * 512) + (size_t)(m0 + row) * 512 + ((ls ^ (row & 7)) * 8);
        adst[i] = r0 * 64;
        bptr[i] = W + (size_t)(n0 + row) * 512 + ((ls ^ (row & 7)) * 8);
        bdst[i] = 8192 + r0 * 64;
    }
    f32x4 acc[4][4] = {};
    for (int step = 0; step < 8; ++step) {
        __syncthreads();   // frag reads of previous step done
        for (int i = 0; i < 4; ++i) {
            gll16(aptr[i], &smem[adst[i]]); aptr[i] += 64;
            gll16(bptr[i], &smem[bdst[i]]); bptr[i] += 64;
        }
        __syncthreads();   // staging complete (vmcnt drain)
        const bf16* sA = smem;
        const bf16* sB = smem + 8192;
        for (int kk = 0; kk < 2; ++kk) {
            bf16x8 af[4], bfr[4];
            int sw = ((kk * 4 + quad) ^ (lo & 7)) * 8;
            for (int t = 0; t < 4; ++t) af[t]  = *(const bf16x8*)&sA[(mw + t * 16 + lo) * 64 + sw];
            for (int t = 0; t < 4; ++t) bfr[t] = *(const bf16x8*)&sB[(nw + t * 16 + lo) * 64 + sw];
            for (int mt = 0; mt < 4; ++mt)
                for (int nt = 0; nt < 4; ++nt)
                    acc[mt][nt] = __builtin_amdgcn_mfma_f32_16x16x32_bf16(af[mt], bfr[nt], acc[mt][nt], 0, 0, 0);
        }
    }
    __syncthreads();
    bf16* sT = smem;
    bool isv = (n0 >= 1024);
    float sc = (n0 < 512) ? QSCALE : 1.f;
    for (int mt = 0; mt < 4; ++mt)
        for (int nt = 0; nt < 4; ++nt) {
            int c = nw + nt * 16 + lo;
            float bv = bias[n0 + c];
            for (int r = 0; r < 4; ++r) {
                int l = mw + mt * 16 + quad * 4 + r;
                float v = (acc[mt][nt][r] + bv) * sc;
                if (isv) sT[c * 136 + l] = (bf16)v;   // [128 c][128 l]
                else     sT[l * 136 + c] = (bf16)v;   // [128 l][128 o]
            }
        }
    __syncthreads();
    int row = tid >> 1, hh = tid & 1;
    if (isv) {
        bf16* dst = vb + (size_t)bz * (512 * 4096) + (size_t)(n0 - 1024 + row) * 4096 + m0;
        for (int j = 0; j < 8; ++j) {
            int ch = hh + j * 2;
            *(bf16x8*)(dst + ch * 8) = *(const bf16x8*)&sT[row * 136 + ch * 8];
        }
    } else {
        bf16* dst = qkT + (size_t)bz * (4096 * 1024) + (size_t)(m0 + row) * 1024 + n0;
        for (int j = 0; j < 8; ++j) {
            int ch = hh + j * 2;
            *(bf16x8*)(dst + ch * 8) = *(const bf16x8*)&sT[row * 136 + ch * 8];
        }
    }
}

// ---------------- proj GEMM (R0/R5-verified dbuf structure): D[m=co][n=l] + bias + resid -> fp32 ----
__global__ __launch_bounds__(256, 3) void k_gemm_proj(
    const bf16* __restrict__ W, const bf16* __restrict__ Bm,
    const float* __restrict__ bias_m,
    float* __restrict__ outf, const float* __restrict__ resid) {
    constexpr int BUF = (64 + 128) * 64;
    __shared__ bf16 smem[2 * BUF];
    int bz = blockIdx.z;
    int m0 = blockIdx.y * 64, n0 = blockIdx.x * 128;
    int tid = threadIdx.x, lane = tid & 63, wave = tid >> 6;
    int lo = lane & 15, quad = lane >> 4;
    int lr = lane >> 3, ls = lane & 7;
    int mw = (wave >> 1) * 32, nw = (wave & 1) * 64;
    const bf16* aptr[2]; int adst[2];
    for (int i = 0; i < 2; ++i) {
        int r0 = wave * 16 + i * 8;
        int row = r0 + lr;
        aptr[i] = W + (size_t)(m0 + row) * 512 + ((ls ^ (row & 7)) * 8);
        adst[i] = r0 * 64;
    }
    const bf16* bptr[4]; int bdst[4];
    for (int i = 0; i < 4; ++i) {
        int r0 = wave * 32 + i * 8;
        int row = r0 + lr;
        bptr[i] = Bm + (size_t)bz * (4096 * 512) + (size_t)(n0 + row) * 512 + ((ls ^ (row & 7)) * 8);
        bdst[i] = 64 * 64 + r0 * 64;
    }
    f32x4 acc[2][4] = {};
    for (int i = 0; i < 2; ++i) { gll16(aptr[i], &smem[adst[i]]); aptr[i] += 64; }
    for (int i = 0; i < 4; ++i) { gll16(bptr[i], &smem[bdst[i]]); bptr[i] += 64; }
    for (int step = 0; step < 8; ++step) {
        int cur = step & 1;
        __syncthreads();
        if (step < 7) {
            bf16* nb = &smem[(cur ^ 1) * BUF];
            for (int i = 0; i < 2; ++i) { gll16(aptr[i], nb + adst[i]); aptr[i] += 64; }
            for (int i = 0; i < 4; ++i) { gll16(bptr[i], nb + bdst[i]); bptr[i] += 64; }
        }
        const bf16* sA = &smem[cur * BUF];
        const bf16* sB = sA + 64 * 64;
        for (int kk = 0; kk < 2; ++kk) {
            bf16x8 af[2], bfr[4];
            int sw = ((kk * 4 + quad) ^ (lo & 7)) * 8;
            for (int t = 0; t < 2; ++t) af[t]  = *(const bf16x8*)&sA[(mw + t * 16 + lo) * 64 + sw];
            for (int t = 0; t < 4; ++t) bfr[t] = *(const bf16x8*)&sB[(nw + t * 16 + lo) * 64 + sw];
            for (int mt = 0; mt < 2; ++mt)
                for (int nt = 0; nt < 4; ++nt)
                    acc[mt][nt] = __builtin_amdgcn_mfma_f32_16x16x32_bf16(af[mt], bfr[nt], acc[mt][nt], 0, 0, 0);
        }
    }
    for (int mt = 0; mt < 2; ++mt) {
        int rowb = m0 + mw + mt * 16 + quad * 4;
        for (int nt = 0; nt < 4; ++nt) {
            int col = n0 + nw + nt * 16 + lo;
            for (int r = 0; r < 4; ++r) {
                int row = rowb + r;
                size_t idx = (size_t)bz * (512 * 4096) + (size_t)row * 4096 + col;
                outf[idx] = acc[mt][nt][r] + bias_m[row] + resid[idx];
            }
        }
    }
}

// ---------------- flash attention: R0 partition, KVBLK=128 (half the barriers) ----------------
// qkT[b][l][1024] (q|k, q pre-scaled to log2 domain), v[b][512][4096] natural.
// Grid 256, block 512 (1 block/CU). Wave w: a=w&3 (32 queries), b2=w>>2 (64 keys of each 128-key tile).
// oacc stays [8][2] (64 f32) -> register state ~= R0's measured 88 VGPR; no spill risk.
// LDS exactly 160 KiB: K dbuf @0 (2x32KB [128 k][128 d]) | V dbuf @65536 (2x32KB [128 vc][128 k]) |
// sPe @131072 (8 waves x [32 q][64 k] bf16, 16B-chunk XOR swizzle, 4KB/wave).
// Merge reuses dead loop regions: sOm @0, sOut @67584, sStat @139264.
__global__ __launch_bounds__(512, 2) void k_attn(const bf16* __restrict__ qkT, const bf16* __restrict__ vmat,
                                                 bf16* __restrict__ attnT) {
    __shared__ __align__(16) char smem[163840];
    bf16* sE = (bf16*)smem;
    int bidx = blockIdx.x;
    int bh = bidx & 7;
    int bb = bh >> 2, h = bh & 3;
    int l0 = (bidx >> 3) * 128;
    int tid = threadIdx.x, lane = tid & 63, wave = tid >> 6;
    int lo = lane & 15, quad = lane >> 4;
    int a = wave & 3, b2 = wave >> 2;
    const bf16* qbase = qkT + ((size_t)bb * 4096 + l0) * 1024 + h * 128;
    const bf16* kbase = qkT + (size_t)bb * 4096 * 1024 + 512 + h * 128;
    const bf16* vbase = vmat + (size_t)(bb * 512 + h * 128) * 4096;
    // ---- stage Q (128x128) into kbuf0, pull frags to regs ----
    for (int i = 0; i < 4; ++i) {
        int r0 = wave * 16 + i * 4;
        int row = r0 + quad;
        gll16(qbase + (size_t)row * 1024 + ((lo ^ (row & 15)) * 8), sE + r0 * 128);
    }
    __syncthreads();
    bf16x8 qf[2][4];
    for (int nt = 0; nt < 2; ++nt) {
        int row = a * 32 + nt * 16 + lo;
        for (int kk = 0; kk < 4; ++kk)
            qf[nt][kk] = *(const bf16x8*)&sE[row * 128 + (((kk * 4 + quad) ^ lo) * 8)];
    }
    __syncthreads();   // all q-frag reads done before K(0) staging overwrites
    // ---- staging descriptors: 4 K + 4 V chunks per wave (4 rows of 256B each) ----
    const bf16* kp[4]; int kdst[4];
    const bf16* vp[4]; int vdst[4];
    for (int i = 0; i < 4; ++i) {
        int r0 = wave * 16 + i * 4;
        int row = r0 + quad;
        kp[i] = kbase + (size_t)row * 1024 + ((lo ^ (row & 15)) * 8);
        kdst[i] = r0 * 128;
        vp[i] = vbase + (size_t)row * 4096 + ((lo ^ (row & 15)) * 8);
        vdst[i] = 32768 + r0 * 128;
    }
    char* sPb = smem + 131072 + wave * 4096;   // [32 q][128 B rows], XOR-swizzled 16B chunks
    int swz8 = lo & 7;
    float l_r[2];
    l_r[0] = l_r[1] = 0.f;
    f32x4 oacc[8][2] = {};
    // prologue: stage K(0), V(0) into buf 0
    for (int i = 0; i < 4; ++i) { gll16(kp[i], sE + kdst[i]); kp[i] += (size_t)128 * 1024; }
    for (int i = 0; i < 4; ++i) { gll16(vp[i], sE + vdst[i]); vp[i] += 128; }
    for (int it = 0; it < 32; ++it) {
        int cur = it & 1;
        __syncthreads();   // buf[cur] staged; readers of buf[cur^1] done
        if (it < 31) {
            int nb = (cur ^ 1) * 16384;
            for (int i = 0; i < 4; ++i) { gll16(kp[i], sE + nb + kdst[i]); kp[i] += (size_t)128 * 1024; }
            for (int i = 0; i < 4; ++i) { gll16(vp[i], sE + nb + vdst[i]); vp[i] += 128; }
        }
        const bf16* sK = sE + cur * 16384;
        const bf16* sV = sE + 32768 + cur * 16384;
        // QK^T + per-mt softmax over the wave's 64-key half (4 x 16 keys)
        for (int mt = 0; mt < 4; ++mt) {
            int krow = b2 * 64 + mt * 16 + lo;
            f32x4 s0 = {}, s1 = {};
            __builtin_amdgcn_s_setprio(1);
            for (int kk = 0; kk < 4; ++kk) {
                bf16x8 kf = *(const bf16x8*)&sK[krow * 128 + (((kk * 4 + quad) ^ lo) * 8)];
                s0 = __builtin_amdgcn_mfma_f32_16x16x32_bf16(kf, qf[0][kk], s0, 0, 0, 0);
                s1 = __builtin_amdgcn_mfma_f32_16x16x32_bf16(kf, qf[1][kk], s1, 0, 0, 0);
            }
            __builtin_amdgcn_s_setprio(0);
            // write P (bf16x4): key local = mt*16 + quad*4 + r -> chunk 2mt+(quad>>1), half quad&1
            int cw = (((2 * mt + (quad >> 1)) ^ swz8) << 4) + ((quad & 1) << 3);
            float sm0 = 0.f, sm1 = 0.f;
            bf16x4 pk;
            for (int r = 0; r < 4; ++r) { float pv = __builtin_amdgcn_exp2f(s0[r]); sm0 += pv; pk[r] = (bf16)pv; }
            *(bf16x4*)&sPb[lo * 128 + cw] = pk;
            for (int r = 0; r < 4; ++r) { float pv = __builtin_amdgcn_exp2f(s1[r]); sm1 += pv; pk[r] = (bf16)pv; }
            *(bf16x4*)&sPb[(16 + lo) * 128 + cw] = pk;
            l_r[0] += sm0;
            l_r[1] += sm1;
        }
        // P frags (B-operand): same-wave LDS round trip (in-order DS pipe), own 64-key slice
        bf16x8 pf[2][2];
        for (int nt = 0; nt < 2; ++nt)
            for (int kk = 0; kk < 2; ++kk)
                pf[nt][kk] = *(const bf16x8*)&sPb[(nt * 16 + lo) * 128 + (((kk * 4 + quad) ^ swz8) << 4)];
        // PV: O^T[vc][q] += V . P over the wave's 64-key half
        __builtin_amdgcn_s_setprio(1);
        for (int mt2 = 0; mt2 < 8; ++mt2) {
            int vrow = mt2 * 16 + lo;
            for (int kk = 0; kk < 2; ++kk) {
                bf16x8 vf = *(const bf16x8*)&sV[vrow * 128 + (((b2 * 8 + kk * 4 + quad) ^ lo) * 8)];
                oacc[mt2][0] = __builtin_amdgcn_mfma_f32_16x16x32_bf16(vf, pf[0][kk], oacc[mt2][0], 0, 0, 0);
                oacc[mt2][1] = __builtin_amdgcn_mfma_f32_16x16x32_bf16(vf, pf[1][kk], oacc[mt2][1], 0, 0, 0);
            }
        }
        __builtin_amdgcn_s_setprio(0);
    }
    // ---- merge: finish deferred l reduction, then O = (O0+O1)/(l0+l1) ----
    for (int nt = 0; nt < 2; ++nt) {
        l_r[nt] += __shfl_xor(l_r[nt], 16);
        l_r[nt] += __shfl_xor(l_r[nt], 32);
    }
    __syncthreads();   // all loop LDS reads done
    float* sStat = (float*)(smem + 139264);   // [128 q][2 halves], in dead V region
    if (quad == 0) {
        for (int nt = 0; nt < 2; ++nt) {
            int qb = a * 32 + nt * 16 + lo;
            sStat[qb * 2 + b2] = l_r[nt];
        }
    }
    __syncthreads();
    float inv[2];
    for (int nt = 0; nt < 2; ++nt) {
        int qb = a * 32 + nt * 16 + lo;
        inv[nt] = 1.f / (sStat[qb * 2] + sStat[qb * 2 + 1]);
    }
    float* sOm = (float*)smem;            // [4 a][128 vc][33] f32 = 67584 B
    bf16* sOut = (bf16*)(smem + 67584);   // [128 q][136] bf16 = 34816 B (ends 102400)
    if (b2 == 1) {
        for (int mt2 = 0; mt2 < 8; ++mt2)
            for (int nt = 0; nt < 2; ++nt)
                for (int r = 0; r < 4; ++r) {
                    int vc = mt2 * 16 + quad * 4 + r;
                    sOm[a * 4224 + vc * 33 + nt * 16 + lo] = oacc[mt2][nt][r];
                }
    }
    __syncthreads();
    if (b2 == 0) {
        for (int mt2 = 0; mt2 < 8; ++mt2)
            for (int nt = 0; nt < 2; ++nt)
                for (int r = 0; r < 4; ++r) {
                    int vc = mt2 * 16 + quad * 4 + r;
                    float v = (oacc[mt2][nt][r] + sOm[a * 4224 + vc * 33 + nt * 16 + lo]) * inv[nt];
                    sOut[(a * 32 + nt * 16 + lo) * 136 + vc] = (bf16)v;
                }
    }
    __syncthreads();
    bf16* dst = attnT + ((size_t)bb * 4096 + l0) * 512 + h * 128;
    for (int i = 0; i < 4; ++i) {
        int row = (tid >> 4) + i * 32;
        int chunk = tid & 15;
        bf16x8 v = *(const bf16x8*)&sOut[row * 136 + chunk * 8];
        *(bf16x8*)(dst + (size_t)row * 512 + chunk * 8) = v;
    }
}

// ---------------- launcher ----------------
extern "C" void kernel_launch(void* const* d_in, const int* in_sizes, int n_in,
                              void* d_out, int out_size, void* d_ws, size_t ws_size,
                              hipStream_t stream) {
    const float* x      = (const float*)d_in[0];
    const float* gn_w   = (const float*)d_in[1];
    const float* gn_b   = (const float*)d_in[2];
    const float* w_qkv  = (const float*)d_in[3];
    const float* b_qkv  = (const float*)d_in[4];
    const float* w_proj = (const float*)d_in[5];
    const float* b_proj = (const float*)d_in[6];
    float* out = (float*)d_out;
    char* ws = (char*)d_ws;
    bf16* wqkv_b  = (bf16*)(ws + 0);
    bf16* wproj_b = (bf16*)(ws + 1572864);
    bf16* xn_t    = (bf16*)(ws + 2097152);
    bf16* qkT     = (bf16*)(ws + 10485760);
    bf16* vb      = (bf16*)(ws + 27262976);
    bf16* attnT   = (bf16*)(ws + 35651584);
    float* part   = (float*)(ws + 44040192);

    k_pre<<<1280, 256, 0, stream>>>(w_qkv, w_proj, x, wqkv_b, wproj_b, part);
    k_gn_norm_t<<<dim3(64, 8, 2), 256, 0, stream>>>(x, gn_w, gn_b, part, xn_t);
    // fused qkv+v: o<1024 -> qkT[l][o] (q scaled), o>=1024 -> vb[c][l]
    k_gemm_qkv<<<dim3(12, 32, 2), 256, 0, stream>>>(xn_t, wqkv_b, b_qkv, qkT, vb);
    k_attn<<<256, 512, 0, stream>>>(qkT, vb, attnT);
    k_gemm_proj<<<dim3(32, 8, 2), 256, 0, stream>>>(wproj_b, attnT, b_proj, out, x);
}

// Round 10
// 187.369 us; speedup vs baseline: 1.3667x; 1.0080x over previous
//
#include <hip/hip_runtime.h>
#include <math.h>

typedef __bf16 bf16;
typedef __bf16 bf16x8 __attribute__((ext_vector_type(8)));
typedef __bf16 bf16x4 __attribute__((ext_vector_type(4)));
typedef float f32x4 __attribute__((ext_vector_type(4)));

// B=2, C=512, L=4096, NH=4, HD=128, GROUPS=32. K of every GEMM = 512.
#define QSCALE (0.08838834764831845f * 1.4426950408889634f)  // 1/sqrt(128) * log2(e)

__device__ __forceinline__ void gll16(const bf16* g, bf16* l) {
    __builtin_amdgcn_global_load_lds((const __attribute__((address_space(1))) void*)g,
                                     (__attribute__((address_space(3))) void*)l, 16, 0, 0);
}

// ---------------- fused: weight fp32->bf16 convert (blocks 0..1023) + GN partial stats (1024..1279) ----
__global__ void k_pre(const float* __restrict__ wqkv, const float* __restrict__ wproj,
                      const float* __restrict__ x,
                      bf16* __restrict__ wqkv_b, bf16* __restrict__ wproj_b,
                      float* __restrict__ part) {
    int blk = blockIdx.x;
    if (blk < 1024) {
        int i = blk * 256 + threadIdx.x;   // float4 index
        const int n1 = (1536 * 512) / 4;
        float4 v;
        bf16* dst;
        if (i < n1) { v = ((const float4*)wqkv)[i];      dst = wqkv_b + (size_t)i * 4; }
        else        { v = ((const float4*)wproj)[i - n1]; dst = wproj_b + (size_t)(i - n1) * 4; }
        bf16x4 o;
        o[0] = (bf16)v.x; o[1] = (bf16)v.y; o[2] = (bf16)v.z; o[3] = (bf16)v.w;
        *(bf16x4*)dst = o;
        return;
    }
    int b2 = blk - 1024;
    int grp = b2 >> 2, p = b2 & 3;
    const float4* src = (const float4*)(x + (size_t)grp * 65536 + (size_t)p * 16384);
    float s = 0.f, ss = 0.f;
    for (int it = 0; it < 16; ++it) {
        float4 v = src[threadIdx.x + it * 256];
        s  += v.x + v.y + v.z + v.w;
        ss += v.x * v.x + v.y * v.y + v.z * v.z + v.w * v.w;
    }
    for (int off = 32; off; off >>= 1) { s += __shfl_down(s, off); ss += __shfl_down(ss, off); }
    __shared__ float rs[4], rss[4];
    int wave = threadIdx.x >> 6;
    if ((threadIdx.x & 63) == 0) { rs[wave] = s; rss[wave] = ss; }
    __syncthreads();
    if (threadIdx.x == 0) {
        part[(grp * 4 + p) * 2]     = rs[0] + rs[1] + rs[2] + rs[3];
        part[(grp * 4 + p) * 2 + 1] = rss[0] + rss[1] + rss[2] + rss[3];
    }
}

// ---------------- GN normalize + transpose (stats finalized in-block): x[b][c][l] -> xn_t[b][l][c] ----
__global__ __launch_bounds__(256) void k_gn_norm_t(const float* __restrict__ x, const float* __restrict__ gw,
                                                   const float* __restrict__ gb, const float* __restrict__ part,
                                                   bf16* __restrict__ xn_t) {
    __shared__ float sX[64 * 69];
    __shared__ float sMean[4], sRstd[4];
    int b = blockIdx.z, c0 = blockIdx.y * 64, l0 = blockIdx.x * 64;
    int t = threadIdx.x;
    if (t < 4) {
        int g = b * 32 + (c0 >> 4) + t;
        float S = 0.f, SS = 0.f;
        for (int p = 0; p < 4; ++p) { S += part[(g * 4 + p) * 2]; SS += part[(g * 4 + p) * 2 + 1]; }
        float mean = S * (1.f / 65536.f);
        float var  = SS * (1.f / 65536.f) - mean * mean;
        sMean[t] = mean;
        sRstd[t] = rsqrtf(var + 1e-5f);
    }
    __syncthreads();
    int cr = t >> 4, lq = t & 15;
    const float* xp = x + ((size_t)(b * 512 + c0)) * 4096 + l0;
    for (int i = 0; i < 4; ++i) {
        int c = cr + i * 16;
        int cg = c0 + c;
        float mean = sMean[c >> 4], rstd = sRstd[c >> 4];
        float ga = gw[cg] * rstd;
        float be = gb[cg] - mean * ga;
        float4 v = *(const float4*)(xp + (size_t)c * 4096 + lq * 4);
        float* d = &sX[c * 69 + lq * 4];
        d[0] = v.x * ga + be; d[1] = v.y * ga + be; d[2] = v.z * ga + be; d[3] = v.w * ga + be;
    }
    __syncthreads();
    int lr = t >> 3, cp = t & 7;
    bf16* dst = xn_t + ((size_t)b * 4096 + l0) * 512 + c0;
    for (int i = 0; i < 2; ++i) {
        int l = lr + i * 32;
        bf16x8 o;
        for (int j = 0; j < 8; ++j) o[j] = (bf16)sX[(cp * 8 + j) * 69 + l];
        *(bf16x8*)(dst + (size_t)l * 512 + cp * 8) = o;
    }
}

// ---------------- fused qkv+v GEMM (m97 structure): out[o][l] for o<1024 -> qkT[l][o]; o>=1024 -> v ----
// BM=BN=128, BK=64, 8 k-steps, single-buffer LDS + 2 barriers/step. T1 XCD-chunked swizzle.
// 768 blocks = 3/CU co-resident (prerequisite that hides the post-stage vmcnt drain).
__global__ __launch_bounds__(256, 3) void k_gemm_qkv(
    const bf16* __restrict__ A, const bf16* __restrict__ W, const float* __restrict__ bias,
    bf16* __restrict__ qkT, bf16* __restrict__ vb) {
    __shared__ bf16 smem[17408];   // stage: A 128x64 @0, B 128x64 @8192 (32KB); epilogue [128][136] 34816B
    int linear = blockIdx.x + 12 * blockIdx.y + 384 * blockIdx.z;
    int swz = (linear & 7) * 96 + (linear >> 3);   // bijective: 768 = 8 * 96
    int n0 = (swz % 12) * 128;
    int m0 = ((swz / 12) % 32) * 128;
    int bz = swz / 384;
    int tid = threadIdx.x, lane = tid & 63, wave = tid >> 6;
    int lo = lane & 15, quad = lane >> 4;
    int lr = lane >> 3, ls = lane & 7;
    int mw = (wave >> 1) * 64, nw = (wave & 1) * 64;
    const bf16* aptr[4]; int adst[4];
    const bf16* bptr[4]; int bdst[4];
    for (int i = 0; i < 4; ++i) {
        int r0 = wave * 32 + i * 8;
        int row = r0 + lr;
        aptr[i] = A + (size_t)bz * (4096 * 512) + (size_t)(m0 + row) * 512 + ((ls ^ (row & 7)) * 8);
        adst[i] = r0 * 64;
        bptr[i] = W + (size_t)(n0 + row) * 512 + ((ls ^ (row & 7)) * 8);
        bdst[i] = 8192 + r0 * 64;
    }
    f32x4 acc[4][4] = {};
    for (int step = 0; step < 8; ++step) {
        __syncthreads();   // frag reads of previous step done
        for (int i = 0; i < 4; ++i) {
            gll16(aptr[i], &smem[adst[i]]); aptr[i] += 64;
            gll16(bptr[i], &smem[bdst[i]]); bptr[i] += 64;
        }
        __syncthreads();   // staging complete (vmcnt drain)
        const bf16* sA = smem;
        const bf16* sB = smem + 8192;
        for (int kk = 0; kk < 2; ++kk) {
            bf16x8 af[4], bfr[4];
            int sw = ((kk * 4 + quad) ^ (lo & 7)) * 8;
            for (int t = 0; t < 4; ++t) af[t]  = *(const bf16x8*)&sA[(mw + t * 16 + lo) * 64 + sw];
            for (int t = 0; t < 4; ++t) bfr[t] = *(const bf16x8*)&sB[(nw + t * 16 + lo) * 64 + sw];
            for (int mt = 0; mt < 4; ++mt)
                for (int nt = 0; nt < 4; ++nt)
                    acc[mt][nt] = __builtin_amdgcn_mfma_f32_16x16x32_bf16(af[mt], bfr[nt], acc[mt][nt], 0, 0, 0);
        }
    }
    __syncthreads();
    bf16* sT = smem;
    bool isv = (n0 >= 1024);
    float sc = (n0 < 512) ? QSCALE : 1.f;
    for (int mt = 0; mt < 4; ++mt)
        for (int nt = 0; nt < 4; ++nt) {
            int c = nw + nt * 16 + lo;
            float bv = bias[n0 + c];
            for (int r = 0; r < 4; ++r) {
                int l = mw + mt * 16 + quad * 4 + r;
                float v = (acc[mt][nt][r] + bv) * sc;
                if (isv) sT[c * 136 + l] = (bf16)v;   // [128 c][128 l]
                else     sT[l * 136 + c] = (bf16)v;   // [128 l][128 o]
            }
        }
    __syncthreads();
    int row = tid >> 1, hh = tid & 1;
    if (isv) {
        bf16* dst = vb + (size_t)bz * (512 * 4096) + (size_t)(n0 - 1024 + row) * 4096 + m0;
        for (int j = 0; j < 8; ++j) {
            int ch = hh + j * 2;
            *(bf16x8*)(dst + ch * 8) = *(const bf16x8*)&sT[row * 136 + ch * 8];
        }
    } else {
        bf16* dst = qkT + (size_t)bz * (4096 * 1024) + (size_t)(m0 + row) * 1024 + n0;
        for (int j = 0; j < 8; ++j) {
            int ch = hh + j * 2;
            *(bf16x8*)(dst + ch * 8) = *(const bf16x8*)&sT[row * 136 + ch * 8];
        }
    }
}

// ---------------- proj GEMM: 128x128 tile + VERIFIED dbuf schedule (prefetch-after-barrier) ----------
// D[m=co][n=l] = sum_k W[co][k]*attnT[l][k] + bias + resid -> fp32 out.
// BM=BN=128, BK=64, double-buffered: the barrier's vmcnt drain waits on loads issued a full
// compute-phase earlier (works at 1 block/CU — R0-proj principle; NOT the m97 2-barrier form,
// which needs 3/CU co-residency and regressed in R7). 32 MFMA : 16 ds_read per step (1.5x better
// ratio than the 64x128 tile). Grid 256 = 1 round, no tail; XCD-chunked swizzle.
__global__ __launch_bounds__(256) void k_gemm_proj(
    const bf16* __restrict__ W, const bf16* __restrict__ Bm,
    const float* __restrict__ bias_m,
    float* __restrict__ outf, const float* __restrict__ resid) {
    constexpr int BUF = (128 + 128) * 64;   // 16384 bf16 per dbuf half
    __shared__ bf16 smem[2 * BUF];          // 64 KB
    int linear = blockIdx.x + 32 * blockIdx.y + 128 * blockIdx.z;
    int swz = (linear & 7) * 32 + (linear >> 3);   // bijective: 256 = 8 * 32
    int n0 = (swz % 32) * 128;
    int m0 = ((swz / 32) % 4) * 128;
    int bz = swz / 128;
    int tid = threadIdx.x, lane = tid & 63, wave = tid >> 6;
    int lo = lane & 15, quad = lane >> 4;
    int lr = lane >> 3, ls = lane & 7;
    int mw = (wave >> 1) * 64, nw = (wave & 1) * 64;
    const bf16* aptr[4]; int adst[4];
    const bf16* bptr[4]; int bdst[4];
    for (int i = 0; i < 4; ++i) {
        int r0 = wave * 32 + i * 8;
        int row = r0 + lr;
        aptr[i] = W + (size_t)(m0 + row) * 512 + ((ls ^ (row & 7)) * 8);
        adst[i] = r0 * 64;
        bptr[i] = Bm + (size_t)bz * (4096 * 512) + (size_t)(n0 + row) * 512 + ((ls ^ (row & 7)) * 8);
        bdst[i] = 8192 + r0 * 64;
    }
    f32x4 acc[4][4] = {};
    // prologue: stage buf0
    for (int i = 0; i < 4; ++i) {
        gll16(aptr[i], &smem[adst[i]]); aptr[i] += 64;
        gll16(bptr[i], &smem[bdst[i]]); bptr[i] += 64;
    }
    for (int step = 0; step < 8; ++step) {
        int cur = step & 1;
        __syncthreads();   // buf[cur] staged (loads issued a full compute-phase ago); prior readers done
        if (step < 7) {
            bf16* nb = &smem[(cur ^ 1) * BUF];
            for (int i = 0; i < 4; ++i) {
                gll16(aptr[i], nb + adst[i]); aptr[i] += 64;
                gll16(bptr[i], nb + bdst[i]); bptr[i] += 64;
            }
        }
        const bf16* sA = &smem[cur * BUF];
        const bf16* sB = sA + 8192;
        for (int kk = 0; kk < 2; ++kk) {
            bf16x8 af[4], bfr[4];
            int sw = ((kk * 4 + quad) ^ (lo & 7)) * 8;
            for (int t = 0; t < 4; ++t) af[t]  = *(const bf16x8*)&sA[(mw + t * 16 + lo) * 64 + sw];
            for (int t = 0; t < 4; ++t) bfr[t] = *(const bf16x8*)&sB[(nw + t * 16 + lo) * 64 + sw];
            for (int mt = 0; mt < 4; ++mt)
                for (int nt = 0; nt < 4; ++nt)
                    acc[mt][nt] = __builtin_amdgcn_mfma_f32_16x16x32_bf16(af[mt], bfr[nt], acc[mt][nt], 0, 0, 0);
        }
    }
    for (int mt = 0; mt < 4; ++mt) {
        int rowb = m0 + mw + mt * 16 + quad * 4;
        for (int nt = 0; nt < 4; ++nt) {
            int col = n0 + nw + nt * 16 + lo;
            for (int r = 0; r < 4; ++r) {
                int row = rowb + r;
                size_t idx = (size_t)bz * (512 * 4096) + (size_t)row * 4096 + col;
                outf[idx] = acc[mt][nt][r] + bias_m[row] + resid[idx];
            }
        }
    }
}

// ---------------- flash attention (128q x 512-thread blocks, fixed-shift softmax) ----------------
// R0-verified kernel (82-86 us across 4 independent benches). Structural plateau for this family:
// occupancy 2x (R1 null), T15 pipeline (R2 null), V-from-global (R3 -73us), 2q x 4k partition
// (R6/R8 VGPR-infeasible), KVBLK=128 (R9 -9us via serialized softmax). DS-pipe floor ~2300 cyc/iter
// of the 3113 measured; remaining gap needs the fully co-designed HK structure.
__global__ __launch_bounds__(512, 2) void k_attn(const bf16* __restrict__ qkT, const bf16* __restrict__ vmat,
                                                 bf16* __restrict__ attnT) {
    // loop:  K dbuf @0 (2x16KB) | V dbuf @32768 (2x16KB) | sPe @65536 (8 waves x [32][40] = 20KB)
    //        sStat @102400 ([128 q][2 halves]{l} = 1KB)
    // merge: sOm @0 ([4 a][128 vc][33] f32 = 66KB) | sOut @67584 ([128 q][136] bf16 = 34KB)
    __shared__ __align__(16) char smem[104448];
    bf16* sE = (bf16*)smem;
    float* sStat = (float*)(smem + 102400);
    int bidx = blockIdx.x;
    int bh = bidx & 7;
    int bb = bh >> 2, h = bh & 3;
    int l0 = (bidx >> 3) * 128;
    int tid = threadIdx.x, lane = tid & 63, wave = tid >> 6;
    int lo = lane & 15, quad = lane >> 4;
    int a = wave & 3, b2 = wave >> 2;
    int lr16 = lane >> 4, ls16 = lane & 15;
    int lr8 = lane >> 3, ls8 = lane & 7;
    const bf16* qbase = qkT + ((size_t)bb * 4096 + l0) * 1024 + h * 128;
    const bf16* kbase = qkT + (size_t)bb * 4096 * 1024 + 512 + h * 128;
    const bf16* vbase = vmat + (size_t)(bb * 512 + h * 128) * 4096;
    // ---- stage Q (128 x 128) into K-dbuf region, pull frags to regs ----
    for (int i = 0; i < 4; ++i) {
        int r0 = wave * 16 + i * 4;
        int row = r0 + lr16;
        gll16(qbase + (size_t)row * 1024 + ((ls16 ^ (row & 15)) * 8), sE + r0 * 128);
    }
    __syncthreads();
    bf16x8 qf[2][4];
    for (int nt = 0; nt < 2; ++nt) {
        int row = a * 32 + nt * 16 + lo;
        for (int kk = 0; kk < 4; ++kk)
            qf[nt][kk] = *(const bf16x8*)&sE[row * 128 + (((kk * 4 + quad) ^ lo) * 8)];
    }
    __syncthreads();   // all q-frag reads done before K prefetch overwrites
    // ---- staging descriptors: 2 K-chunks + 2 V-chunks per wave ----
    const bf16* kptr[2]; int kdst[2];
    const bf16* vptr[2]; int vdst[2];
    for (int i = 0; i < 2; ++i) {
        int r0 = wave * 8 + i * 4;
        int row = r0 + lr16;
        kptr[i] = kbase + (size_t)row * 1024 + ((ls16 ^ (row & 15)) * 8);
        kdst[i] = r0 * 128;
        int s0 = wave * 16 + i * 8;
        int srow = s0 + lr8;
        vptr[i] = vbase + (size_t)srow * 4096 + ((ls8 ^ (srow & 7)) * 8);
        vdst[i] = s0 * 64;
    }
    bf16* sPe = (bf16*)(smem + 65536) + wave * 1280;   // [32 q][40]
    float l_r[2];
    l_r[0] = l_r[1] = 0.f;
    f32x4 oacc[8][2] = {};
    // prologue prefetch (buf 0)
    for (int i = 0; i < 2; ++i) { gll16(kptr[i], sE + kdst[i]); kptr[i] += (size_t)64 * 1024; }
    for (int i = 0; i < 2; ++i) { gll16(vptr[i], sE + 16384 + vdst[i]); vptr[i] += 64; }
    for (int it = 0; it < 64; ++it) {
        int cur = it & 1;
        __syncthreads();   // buf[cur] staged; readers of buf[cur^1] done
        if (it < 63) {
            bf16* nk = sE + (cur ^ 1) * 8192;
            bf16* nv = sE + 16384 + (cur ^ 1) * 8192;
            for (int i = 0; i < 2; ++i) { gll16(kptr[i], nk + kdst[i]); kptr[i] += (size_t)64 * 1024; }
            for (int i = 0; i < 2; ++i) { gll16(vptr[i], nv + vdst[i]); vptr[i] += 64; }
        }
        const bf16* sK = sE + cur * 8192;
        const bf16* sV = sE + 16384 + cur * 8192;
        // S^T[key][q]: wave's 32-key half x its 32 queries
        f32x4 s[2][2];
        for (int mt = 0; mt < 2; ++mt) {
            int krow = b2 * 32 + mt * 16 + lo;
            bf16x8 kf[4];
            for (int kk = 0; kk < 4; ++kk)
                kf[kk] = *(const bf16x8*)&sK[krow * 128 + (((kk * 4 + quad) ^ lo) * 8)];
            for (int nt = 0; nt < 2; ++nt) {
                f32x4 acc = {};
                for (int kk = 0; kk < 4; ++kk)
                    acc = __builtin_amdgcn_mfma_f32_16x16x32_bf16(kf[kk], qf[nt][kk], acc, 0, 0, 0);
                s[mt][nt] = acc;
            }
        }
        // fixed-shift softmax: P = exp2(s); l accumulated per-lane (reduced at merge)
        for (int nt = 0; nt < 2; ++nt) {
            float sm = 0.f;
            for (int mt = 0; mt < 2; ++mt) {
                bf16x4 pk;
                for (int r = 0; r < 4; ++r) {
                    float pv = __builtin_amdgcn_exp2f(s[mt][nt][r]);
                    sm += pv;
                    pk[r] = (bf16)pv;
                }
                *(bf16x4*)&sPe[(nt * 16 + lo) * 40 + mt * 16 + quad * 4] = pk;
            }
            l_r[nt] += sm;
        }
        // P frags (B-operand) via same-wave LDS round trip (in-order DS pipe)
        bf16x8 pf[2];
        for (int nt = 0; nt < 2; ++nt)
            pf[nt] = *(const bf16x8*)&sPe[(nt * 16 + lo) * 40 + quad * 8];
        // O^T[vc][q] += V . P over the wave's 32-key half
        for (int mt2 = 0; mt2 < 8; ++mt2) {
            bf16x8 vf = *(const bf16x8*)&sV[(mt2 * 16 + lo) * 64 + (((b2 * 4 + quad) ^ (lo & 7)) * 8)];
            for (int nt = 0; nt < 2; ++nt)
                oacc[mt2][nt] = __builtin_amdgcn_mfma_f32_16x16x32_bf16(vf, pf[nt], oacc[mt2][nt], 0, 0, 0);
        }
    }
    // ---- merge: finish deferred l reduction, then O = (O0+O1)/(l0+l1) ----
    for (int nt = 0; nt < 2; ++nt) {
        l_r[nt] += __shfl_xor(l_r[nt], 16);
        l_r[nt] += __shfl_xor(l_r[nt], 32);
    }
    __syncthreads();
    if (quad == 0) {
        for (int nt = 0; nt < 2; ++nt) {
            int qb = a * 32 + nt * 16 + lo;
            sStat[qb * 2 + b2] = l_r[nt];
        }
    }
    __syncthreads();
    float inv[2];
    for (int nt = 0; nt < 2; ++nt) {
        int qb = a * 32 + nt * 16 + lo;
        inv[nt] = 1.f / (sStat[qb * 2] + sStat[qb * 2 + 1]);
    }
    float* sOm = (float*)smem;            // [4 a][128 vc][33]
    bf16* sOut = (bf16*)(smem + 67584);   // [128 q][136]
    if (b2 == 1) {
        for (int mt2 = 0; mt2 < 8; ++mt2)
            for (int nt = 0; nt < 2; ++nt)
                for (int r = 0; r < 4; ++r) {
                    int vc = mt2 * 16 + quad * 4 + r;
                    sOm[a * 4224 + vc * 33 + nt * 16 + lo] = oacc[mt2][nt][r];
                }
    }
    __syncthreads();
    if (b2 == 0) {
        for (int mt2 = 0; mt2 < 8; ++mt2)
            for (int nt = 0; nt < 2; ++nt)
                for (int r = 0; r < 4; ++r) {
                    int vc = mt2 * 16 + quad * 4 + r;
                    float v = (oacc[mt2][nt][r] + sOm[a * 4224 + vc * 33 + nt * 16 + lo]) * inv[nt];
                    sOut[(a * 32 + nt * 16 + lo) * 136 + vc] = (bf16)v;
                }
    }
    __syncthreads();
    bf16* dst = attnT + ((size_t)bb * 4096 + l0) * 512 + h * 128;
    for (int i = 0; i < 4; ++i) {
        int row = (tid >> 4) + i * 32;
        int chunk = tid & 15;
        bf16x8 v = *(const bf16x8*)&sOut[row * 136 + chunk * 8];
        *(bf16x8*)(dst + (size_t)row * 512 + chunk * 8) = v;
    }
}

// ---------------- launcher ----------------
extern "C" void kernel_launch(void* const* d_in, const int* in_sizes, int n_in,
                              void* d_out, int out_size, void* d_ws, size_t ws_size,
                              hipStream_t stream) {
    const float* x      = (const float*)d_in[0];
    const float* gn_w   = (const float*)d_in[1];
    const float* gn_b   = (const float*)d_in[2];
    const float* w_qkv  = (const float*)d_in[3];
    const float* b_qkv  = (const float*)d_in[4];
    const float* w_proj = (const float*)d_in[5];
    const float* b_proj = (const float*)d_in[6];
    float* out = (float*)d_out;
    char* ws = (char*)d_ws;
    bf16* wqkv_b  = (bf16*)(ws + 0);
    bf16* wproj_b = (bf16*)(ws + 1572864);
    bf16* xn_t    = (bf16*)(ws + 2097152);
    bf16* qkT     = (bf16*)(ws + 10485760);
    bf16* vb      = (bf16*)(ws + 27262976);
    bf16* attnT   = (bf16*)(ws + 35651584);
    float* part   = (float*)(ws + 44040192);

    k_pre<<<1280, 256, 0, stream>>>(w_qkv, w_proj, x, wqkv_b, wproj_b, part);
    k_gn_norm_t<<<dim3(64, 8, 2), 256, 0, stream>>>(x, gn_w, gn_b, part, xn_t);
    // fused qkv+v: o<1024 -> qkT[l][o] (q scaled), o>=1024 -> vb[c][l]
    k_gemm_qkv<<<dim3(12, 32, 2), 256, 0, stream>>>(xn_t, wqkv_b, b_qkv, qkT, vb);
    k_attn<<<256, 512, 0, stream>>>(qkT, vb, attnT);
    k_gemm_proj<<<dim3(32, 4, 2), 256, 0, stream>>>(wproj_b, attnT, b_proj, out, x);
}

// Round 11
// 183.280 us; speedup vs baseline: 1.3972x; 1.0223x over previous
//
#include <hip/hip_runtime.h>
#include <math.h>

typedef __bf16 bf16;
typedef __bf16 bf16x8 __attribute__((ext_vector_type(8)));
typedef __bf16 bf16x4 __attribute__((ext_vector_type(4)));
typedef float f32x4 __attribute__((ext_vector_type(4)));

// B=2, C=512, L=4096, NH=4, HD=128, GROUPS=32. K of every GEMM = 512.
#define QSCALE (0.08838834764831845f * 1.4426950408889634f)  // 1/sqrt(128) * log2(e)

__device__ __forceinline__ void gll16(const bf16* g, bf16* l) {
    __builtin_amdgcn_global_load_lds((const __attribute__((address_space(1))) void*)g,
                                     (__attribute__((address_space(3))) void*)l, 16, 0, 0);
}

// ---------------- fused: weight fp32->bf16 convert (blocks 0..1023) + GN partial stats (1024..1279) ----
__global__ void k_pre(const float* __restrict__ wqkv, const float* __restrict__ wproj,
                      const float* __restrict__ x,
                      bf16* __restrict__ wqkv_b, bf16* __restrict__ wproj_b,
                      float* __restrict__ part) {
    int blk = blockIdx.x;
    if (blk < 1024) {
        int i = blk * 256 + threadIdx.x;   // float4 index
        const int n1 = (1536 * 512) / 4;
        float4 v;
        bf16* dst;
        if (i < n1) { v = ((const float4*)wqkv)[i];      dst = wqkv_b + (size_t)i * 4; }
        else        { v = ((const float4*)wproj)[i - n1]; dst = wproj_b + (size_t)(i - n1) * 4; }
        bf16x4 o;
        o[0] = (bf16)v.x; o[1] = (bf16)v.y; o[2] = (bf16)v.z; o[3] = (bf16)v.w;
        *(bf16x4*)dst = o;
        return;
    }
    int b2 = blk - 1024;
    int grp = b2 >> 2, p = b2 & 3;
    const float4* src = (const float4*)(x + (size_t)grp * 65536 + (size_t)p * 16384);
    float s = 0.f, ss = 0.f;
    for (int it = 0; it < 16; ++it) {
        float4 v = src[threadIdx.x + it * 256];
        s  += v.x + v.y + v.z + v.w;
        ss += v.x * v.x + v.y * v.y + v.z * v.z + v.w * v.w;
    }
    for (int off = 32; off; off >>= 1) { s += __shfl_down(s, off); ss += __shfl_down(ss, off); }
    __shared__ float rs[4], rss[4];
    int wave = threadIdx.x >> 6;
    if ((threadIdx.x & 63) == 0) { rs[wave] = s; rss[wave] = ss; }
    __syncthreads();
    if (threadIdx.x == 0) {
        part[(grp * 4 + p) * 2]     = rs[0] + rs[1] + rs[2] + rs[3];
        part[(grp * 4 + p) * 2 + 1] = rss[0] + rss[1] + rss[2] + rss[3];
    }
}

// ---------------- GN normalize + transpose (stats finalized in-block): x[b][c][l] -> xn_t[b][l][c] ----
__global__ __launch_bounds__(256) void k_gn_norm_t(const float* __restrict__ x, const float* __restrict__ gw,
                                                   const float* __restrict__ gb, const float* __restrict__ part,
                                                   bf16* __restrict__ xn_t) {
    __shared__ float sX[64 * 69];
    __shared__ float sMean[4], sRstd[4];
    int b = blockIdx.z, c0 = blockIdx.y * 64, l0 = blockIdx.x * 64;
    int t = threadIdx.x;
    if (t < 4) {
        int g = b * 32 + (c0 >> 4) + t;
        float S = 0.f, SS = 0.f;
        for (int p = 0; p < 4; ++p) { S += part[(g * 4 + p) * 2]; SS += part[(g * 4 + p) * 2 + 1]; }
        float mean = S * (1.f / 65536.f);
        float var  = SS * (1.f / 65536.f) - mean * mean;
        sMean[t] = mean;
        sRstd[t] = rsqrtf(var + 1e-5f);
    }
    __syncthreads();
    int cr = t >> 4, lq = t & 15;
    const float* xp = x + ((size_t)(b * 512 + c0)) * 4096 + l0;
    for (int i = 0; i < 4; ++i) {
        int c = cr + i * 16;
        int cg = c0 + c;
        float mean = sMean[c >> 4], rstd = sRstd[c >> 4];
        float ga = gw[cg] * rstd;
        float be = gb[cg] - mean * ga;
        float4 v = *(const float4*)(xp + (size_t)c * 4096 + lq * 4);
        float* d = &sX[c * 69 + lq * 4];
        d[0] = v.x * ga + be; d[1] = v.y * ga + be; d[2] = v.z * ga + be; d[3] = v.w * ga + be;
    }
    __syncthreads();
    int lr = t >> 3, cp = t & 7;
    bf16* dst = xn_t + ((size_t)b * 4096 + l0) * 512 + c0;
    for (int i = 0; i < 2; ++i) {
        int l = lr + i * 32;
        bf16x8 o;
        for (int j = 0; j < 8; ++j) o[j] = (bf16)sX[(cp * 8 + j) * 69 + l];
        *(bf16x8*)(dst + (size_t)l * 512 + cp * 8) = o;
    }
}

// ---------------- fused qkv+v GEMM (m97 structure): out[o][l] for o<1024 -> qkT[l][o]; o>=1024 -> v ----
// BM=BN=128, BK=64, 8 k-steps, single-buffer LDS + 2 barriers/step. T1 XCD-chunked swizzle.
// 768 blocks = 3/CU co-resident (prerequisite that hides the post-stage vmcnt drain).
__global__ __launch_bounds__(256, 3) void k_gemm_qkv(
    const bf16* __restrict__ A, const bf16* __restrict__ W, const float* __restrict__ bias,
    bf16* __restrict__ qkT, bf16* __restrict__ vb) {
    __shared__ bf16 smem[17408];   // stage: A 128x64 @0, B 128x64 @8192 (32KB); epilogue [128][136] 34816B
    int linear = blockIdx.x + 12 * blockIdx.y + 384 * blockIdx.z;
    int swz = (linear & 7) * 96 + (linear >> 3);   // bijective: 768 = 8 * 96
    int n0 = (swz % 12) * 128;
    int m0 = ((swz / 12) % 32) * 128;
    int bz = swz / 384;
    int tid = threadIdx.x, lane = tid & 63, wave = tid >> 6;
    int lo = lane & 15, quad = lane >> 4;
    int lr = lane >> 3, ls = lane & 7;
    int mw = (wave >> 1) * 64, nw = (wave & 1) * 64;
    const bf16* aptr[4]; int adst[4];
    const bf16* bptr[4]; int bdst[4];
    for (int i = 0; i < 4; ++i) {
        int r0 = wave * 32 + i * 8;
        int row = r0 + lr;
        aptr[i] = A + (size_t)bz * (4096 * 512) + (size_t)(m0 + row) * 512 + ((ls ^ (row & 7)) * 8);
        adst[i] = r0 * 64;
        bptr[i] = W + (size_t)(n0 + row) * 512 + ((ls ^ (row & 7)) * 8);
        bdst[i] = 8192 + r0 * 64;
    }
    f32x4 acc[4][4] = {};
    for (int step = 0; step < 8; ++step) {
        __syncthreads();   // frag reads of previous step done
        for (int i = 0; i < 4; ++i) {
            gll16(aptr[i], &smem[adst[i]]); aptr[i] += 64;
            gll16(bptr[i], &smem[bdst[i]]); bptr[i] += 64;
        }
        __syncthreads();   // staging complete (vmcnt drain)
        const bf16* sA = smem;
        const bf16* sB = smem + 8192;
        for (int kk = 0; kk < 2; ++kk) {
            bf16x8 af[4], bfr[4];
            int sw = ((kk * 4 + quad) ^ (lo & 7)) * 8;
            for (int t = 0; t < 4; ++t) af[t]  = *(const bf16x8*)&sA[(mw + t * 16 + lo) * 64 + sw];
            for (int t = 0; t < 4; ++t) bfr[t] = *(const bf16x8*)&sB[(nw + t * 16 + lo) * 64 + sw];
            for (int mt = 0; mt < 4; ++mt)
                for (int nt = 0; nt < 4; ++nt)
                    acc[mt][nt] = __builtin_amdgcn_mfma_f32_16x16x32_bf16(af[mt], bfr[nt], acc[mt][nt], 0, 0, 0);
        }
    }
    __syncthreads();
    bf16* sT = smem;
    bool isv = (n0 >= 1024);
    float sc = (n0 < 512) ? QSCALE : 1.f;
    for (int mt = 0; mt < 4; ++mt)
        for (int nt = 0; nt < 4; ++nt) {
            int c = nw + nt * 16 + lo;
            float bv = bias[n0 + c];
            for (int r = 0; r < 4; ++r) {
                int l = mw + mt * 16 + quad * 4 + r;
                float v = (acc[mt][nt][r] + bv) * sc;
                if (isv) sT[c * 136 + l] = (bf16)v;   // [128 c][128 l]
                else     sT[l * 136 + c] = (bf16)v;   // [128 l][128 o]
            }
        }
    __syncthreads();
    int row = tid >> 1, hh = tid & 1;
    if (isv) {
        bf16* dst = vb + (size_t)bz * (512 * 4096) + (size_t)(n0 - 1024 + row) * 4096 + m0;
        for (int j = 0; j < 8; ++j) {
            int ch = hh + j * 2;
            *(bf16x8*)(dst + ch * 8) = *(const bf16x8*)&sT[row * 136 + ch * 8];
        }
    } else {
        bf16* dst = qkT + (size_t)bz * (4096 * 1024) + (size_t)(m0 + row) * 1024 + n0;
        for (int j = 0; j < 8; ++j) {
            int ch = hh + j * 2;
            *(bf16x8*)(dst + ch * 8) = *(const bf16x8*)&sT[row * 136 + ch * 8];
        }
    }
}

// ---------------- proj GEMM: 128x128 tile + VERIFIED dbuf schedule (prefetch-after-barrier) ----------
__global__ __launch_bounds__(256) void k_gemm_proj(
    const bf16* __restrict__ W, const bf16* __restrict__ Bm,
    const float* __restrict__ bias_m,
    float* __restrict__ outf, const float* __restrict__ resid) {
    constexpr int BUF = (128 + 128) * 64;   // 16384 bf16 per dbuf half
    __shared__ bf16 smem[2 * BUF];          // 64 KB
    int linear = blockIdx.x + 32 * blockIdx.y + 128 * blockIdx.z;
    int swz = (linear & 7) * 32 + (linear >> 3);   // bijective: 256 = 8 * 32
    int n0 = (swz % 32) * 128;
    int m0 = ((swz / 32) % 4) * 128;
    int bz = swz / 128;
    int tid = threadIdx.x, lane = tid & 63, wave = tid >> 6;
    int lo = lane & 15, quad = lane >> 4;
    int lr = lane >> 3, ls = lane & 7;
    int mw = (wave >> 1) * 64, nw = (wave & 1) * 64;
    const bf16* aptr[4]; int adst[4];
    const bf16* bptr[4]; int bdst[4];
    for (int i = 0; i < 4; ++i) {
        int r0 = wave * 32 + i * 8;
        int row = r0 + lr;
        aptr[i] = W + (size_t)(m0 + row) * 512 + ((ls ^ (row & 7)) * 8);
        adst[i] = r0 * 64;
        bptr[i] = Bm + (size_t)bz * (4096 * 512) + (size_t)(n0 + row) * 512 + ((ls ^ (row & 7)) * 8);
        bdst[i] = 8192 + r0 * 64;
    }
    f32x4 acc[4][4] = {};
    // prologue: stage buf0
    for (int i = 0; i < 4; ++i) {
        gll16(aptr[i], &smem[adst[i]]); aptr[i] += 64;
        gll16(bptr[i], &smem[bdst[i]]); bptr[i] += 64;
    }
    for (int step = 0; step < 8; ++step) {
        int cur = step & 1;
        __syncthreads();   // buf[cur] staged (loads issued a full compute-phase ago); prior readers done
        if (step < 7) {
            bf16* nb = &smem[(cur ^ 1) * BUF];
            for (int i = 0; i < 4; ++i) {
                gll16(aptr[i], nb + adst[i]); aptr[i] += 64;
                gll16(bptr[i], nb + bdst[i]); bptr[i] += 64;
            }
        }
        const bf16* sA = &smem[cur * BUF];
        const bf16* sB = sA + 8192;
        for (int kk = 0; kk < 2; ++kk) {
            bf16x8 af[4], bfr[4];
            int sw = ((kk * 4 + quad) ^ (lo & 7)) * 8;
            for (int t = 0; t < 4; ++t) af[t]  = *(const bf16x8*)&sA[(mw + t * 16 + lo) * 64 + sw];
            for (int t = 0; t < 4; ++t) bfr[t] = *(const bf16x8*)&sB[(nw + t * 16 + lo) * 64 + sw];
            for (int mt = 0; mt < 4; ++mt)
                for (int nt = 0; nt < 4; ++nt)
                    acc[mt][nt] = __builtin_amdgcn_mfma_f32_16x16x32_bf16(af[mt], bfr[nt], acc[mt][nt], 0, 0, 0);
        }
    }
    for (int mt = 0; mt < 4; ++mt) {
        int rowb = m0 + mw + mt * 16 + quad * 4;
        for (int nt = 0; nt < 4; ++nt) {
            int col = n0 + nw + nt * 16 + lo;
            for (int r = 0; r < 4; ++r) {
                int row = rowb + r;
                size_t idx = (size_t)bz * (512 * 4096) + (size_t)row * 4096 + col;
                outf[idx] = acc[mt][nt][r] + bias_m[row] + resid[idx];
            }
        }
    }
}

// ---------------- flash attention: R0 partition, KVBLK=128, BATCHED softmax ----------------
// R9 retry with the regression cause removed: R9 interleaved exp2 per-mt, serializing 4 MFMA-latency
// waits/iter; here all 16 QK^T MFMAs issue first into s[4][2], then ONE batched softmax phase (single
// wait, like R0), then PV. Keeps R9's wins: 32 iterations (half the barrier drains), conflicts 2.5M.
// Wave w: a=w&3 (32 q), b2=w>>2 (64 keys of each 128-key tile). oacc [8][2] -> no spill (R9: VGPR 96;
// +24 live f32 for s[4][2] stays under the 128 cap at 2 waves/SIMD).
// LDS exactly 160 KiB: K dbuf @0 (2x32KB) | V dbuf @65536 (2x32KB) | sPe @131072 (8 x [32 q][64 k]).
__global__ __launch_bounds__(512, 2) void k_attn(const bf16* __restrict__ qkT, const bf16* __restrict__ vmat,
                                                 bf16* __restrict__ attnT) {
    __shared__ __align__(16) char smem[163840];
    bf16* sE = (bf16*)smem;
    int bidx = blockIdx.x;
    int bh = bidx & 7;
    int bb = bh >> 2, h = bh & 3;
    int l0 = (bidx >> 3) * 128;
    int tid = threadIdx.x, lane = tid & 63, wave = tid >> 6;
    int lo = lane & 15, quad = lane >> 4;
    int a = wave & 3, b2 = wave >> 2;
    const bf16* qbase = qkT + ((size_t)bb * 4096 + l0) * 1024 + h * 128;
    const bf16* kbase = qkT + (size_t)bb * 4096 * 1024 + 512 + h * 128;
    const bf16* vbase = vmat + (size_t)(bb * 512 + h * 128) * 4096;
    // ---- stage Q (128x128) into kbuf0, pull frags to regs ----
    for (int i = 0; i < 4; ++i) {
        int r0 = wave * 16 + i * 4;
        int row = r0 + quad;
        gll16(qbase + (size_t)row * 1024 + ((lo ^ (row & 15)) * 8), sE + r0 * 128);
    }
    __syncthreads();
    bf16x8 qf[2][4];
    for (int nt = 0; nt < 2; ++nt) {
        int row = a * 32 + nt * 16 + lo;
        for (int kk = 0; kk < 4; ++kk)
            qf[nt][kk] = *(const bf16x8*)&sE[row * 128 + (((kk * 4 + quad) ^ lo) * 8)];
    }
    __syncthreads();   // all q-frag reads done before K(0) staging overwrites
    // ---- staging descriptors: 4 K + 4 V chunks per wave (4 rows of 256B each) ----
    const bf16* kp[4]; int kdst[4];
    const bf16* vp[4]; int vdst[4];
    for (int i = 0; i < 4; ++i) {
        int r0 = wave * 16 + i * 4;
        int row = r0 + quad;
        kp[i] = kbase + (size_t)row * 1024 + ((lo ^ (row & 15)) * 8);
        kdst[i] = r0 * 128;
        vp[i] = vbase + (size_t)row * 4096 + ((lo ^ (row & 15)) * 8);
        vdst[i] = 32768 + r0 * 128;
    }
    char* sPb = smem + 131072 + wave * 4096;   // [32 q][128 B rows], XOR-swizzled 16B chunks
    int swz8 = lo & 7;
    float l_r[2];
    l_r[0] = l_r[1] = 0.f;
    f32x4 oacc[8][2] = {};
    // prologue: stage K(0), V(0) into buf 0
    for (int i = 0; i < 4; ++i) { gll16(kp[i], sE + kdst[i]); kp[i] += (size_t)128 * 1024; }
    for (int i = 0; i < 4; ++i) { gll16(vp[i], sE + vdst[i]); vp[i] += 128; }
    for (int it = 0; it < 32; ++it) {
        int cur = it & 1;
        __syncthreads();   // buf[cur] staged; readers of buf[cur^1] done
        if (it < 31) {
            int nb = (cur ^ 1) * 16384;
            for (int i = 0; i < 4; ++i) { gll16(kp[i], sE + nb + kdst[i]); kp[i] += (size_t)128 * 1024; }
            for (int i = 0; i < 4; ++i) { gll16(vp[i], sE + nb + vdst[i]); vp[i] += 128; }
        }
        const bf16* sK = sE + cur * 16384;
        const bf16* sV = sE + 32768 + cur * 16384;
        // phase 1: ALL QK^T MFMAs (16) over the wave's 64-key half -> s[4][2]; no intermediate waits
        f32x4 s[4][2];
        __builtin_amdgcn_s_setprio(1);
        for (int mt = 0; mt < 4; ++mt) {
            int krow = b2 * 64 + mt * 16 + lo;
            f32x4 s0 = {}, s1 = {};
            for (int kk = 0; kk < 4; ++kk) {
                bf16x8 kf = *(const bf16x8*)&sK[krow * 128 + (((kk * 4 + quad) ^ lo) * 8)];
                s0 = __builtin_amdgcn_mfma_f32_16x16x32_bf16(kf, qf[0][kk], s0, 0, 0, 0);
                s1 = __builtin_amdgcn_mfma_f32_16x16x32_bf16(kf, qf[1][kk], s1, 0, 0, 0);
            }
            s[mt][0] = s0;
            s[mt][1] = s1;
        }
        __builtin_amdgcn_s_setprio(0);
        // phase 2: batched softmax (one wait for the MFMA block, like R0)
        for (int mt = 0; mt < 4; ++mt) {
            int cw = (((2 * mt + (quad >> 1)) ^ swz8) << 4) + ((quad & 1) << 3);
            float sm0 = 0.f, sm1 = 0.f;
            bf16x4 pk;
            for (int r = 0; r < 4; ++r) { float pv = __builtin_amdgcn_exp2f(s[mt][0][r]); sm0 += pv; pk[r] = (bf16)pv; }
            *(bf16x4*)&sPb[lo * 128 + cw] = pk;
            for (int r = 0; r < 4; ++r) { float pv = __builtin_amdgcn_exp2f(s[mt][1][r]); sm1 += pv; pk[r] = (bf16)pv; }
            *(bf16x4*)&sPb[(16 + lo) * 128 + cw] = pk;
            l_r[0] += sm0;
            l_r[1] += sm1;
        }
        // P frags (B-operand): same-wave LDS round trip (in-order DS pipe), own 64-key slice
        bf16x8 pf[2][2];
        for (int nt = 0; nt < 2; ++nt)
            for (int kk = 0; kk < 2; ++kk)
                pf[nt][kk] = *(const bf16x8*)&sPb[(nt * 16 + lo) * 128 + (((kk * 4 + quad) ^ swz8) << 4)];
        // PV: O^T[vc][q] += V . P over the wave's 64-key half
        __builtin_amdgcn_s_setprio(1);
        for (int mt2 = 0; mt2 < 8; ++mt2) {
            int vrow = mt2 * 16 + lo;
            for (int kk = 0; kk < 2; ++kk) {
                bf16x8 vf = *(const bf16x8*)&sV[vrow * 128 + (((b2 * 8 + kk * 4 + quad) ^ lo) * 8)];
                oacc[mt2][0] = __builtin_amdgcn_mfma_f32_16x16x32_bf16(vf, pf[0][kk], oacc[mt2][0], 0, 0, 0);
                oacc[mt2][1] = __builtin_amdgcn_mfma_f32_16x16x32_bf16(vf, pf[1][kk], oacc[mt2][1], 0, 0, 0);
            }
        }
        __builtin_amdgcn_s_setprio(0);
    }
    // ---- merge: finish deferred l reduction, then O = (O0+O1)/(l0+l1) ----
    for (int nt = 0; nt < 2; ++nt) {
        l_r[nt] += __shfl_xor(l_r[nt], 16);
        l_r[nt] += __shfl_xor(l_r[nt], 32);
    }
    __syncthreads();   // all loop LDS reads done
    float* sStat = (float*)(smem + 139264);   // [128 q][2 halves], in dead V region
    if (quad == 0) {
        for (int nt = 0; nt < 2; ++nt) {
            int qb = a * 32 + nt * 16 + lo;
            sStat[qb * 2 + b2] = l_r[nt];
        }
    }
    __syncthreads();
    float inv[2];
    for (int nt = 0; nt < 2; ++nt) {
        int qb = a * 32 + nt * 16 + lo;
        inv[nt] = 1.f / (sStat[qb * 2] + sStat[qb * 2 + 1]);
    }
    float* sOm = (float*)smem;            // [4 a][128 vc][33] f32 = 67584 B
    bf16* sOut = (bf16*)(smem + 67584);   // [128 q][136] bf16 = 34816 B (ends 102400)
    if (b2 == 1) {
        for (int mt2 = 0; mt2 < 8; ++mt2)
            for (int nt = 0; nt < 2; ++nt)
                for (int r = 0; r < 4; ++r) {
                    int vc = mt2 * 16 + quad * 4 + r;
                    sOm[a * 4224 + vc * 33 + nt * 16 + lo] = oacc[mt2][nt][r];
                }
    }
    __syncthreads();
    if (b2 == 0) {
        for (int mt2 = 0; mt2 < 8; ++mt2)
            for (int nt = 0; nt < 2; ++nt)
                for (int r = 0; r < 4; ++r) {
                    int vc = mt2 * 16 + quad * 4 + r;
                    float v = (oacc[mt2][nt][r] + sOm[a * 4224 + vc * 33 + nt * 16 + lo]) * inv[nt];
                    sOut[(a * 32 + nt * 16 + lo) * 136 + vc] = (bf16)v;
                }
    }
    __syncthreads();
    bf16* dst = attnT + ((size_t)bb * 4096 + l0) * 512 + h * 128;
    for (int i = 0; i < 4; ++i) {
        int row = (tid >> 4) + i * 32;
        int chunk = tid & 15;
        bf16x8 v = *(const bf16x8*)&sOut[row * 136 + chunk * 8];
        *(bf16x8*)(dst + (size_t)row * 512 + chunk * 8) = v;
    }
}

// ---------------- launcher ----------------
extern "C" void kernel_launch(void* const* d_in, const int* in_sizes, int n_in,
                              void* d_out, int out_size, void* d_ws, size_t ws_size,
                              hipStream_t stream) {
    const float* x      = (const float*)d_in[0];
    const float* gn_w   = (const float*)d_in[1];
    const float* gn_b   = (const float*)d_in[2];
    const float* w_qkv  = (const float*)d_in[3];
    const float* b_qkv  = (const float*)d_in[4];
    const float* w_proj = (const float*)d_in[5];
    const float* b_proj = (const float*)d_in[6];
    float* out = (float*)d_out;
    char* ws = (char*)d_ws;
    bf16* wqkv_b  = (bf16*)(ws + 0);
    bf16* wproj_b = (bf16*)(ws + 1572864);
    bf16* xn_t    = (bf16*)(ws + 2097152);
    bf16* qkT     = (bf16*)(ws + 10485760);
    bf16* vb      = (bf16*)(ws + 27262976);
    bf16* attnT   = (bf16*)(ws + 35651584);
    float* part   = (float*)(ws + 44040192);

    k_pre<<<1280, 256, 0, stream>>>(w_qkv, w_proj, x, wqkv_b, wproj_b, part);
    k_gn_norm_t<<<dim3(64, 8, 2), 256, 0, stream>>>(x, gn_w, gn_b, part, xn_t);
    // fused qkv+v: o<1024 -> qkT[l][o] (q scaled), o>=1024 -> vb[c][l]
    k_gemm_qkv<<<dim3(12, 32, 2), 256, 0, stream>>>(xn_t, wqkv_b, b_qkv, qkT, vb);
    k_attn<<<256, 512, 0, stream>>>(qkT, vb, attnT);
    k_gemm_proj<<<dim3(32, 4, 2), 256, 0, stream>>>(wproj_b, attnT, b_proj, out, x);
}